// Round 1
// baseline (3294.456 us; speedup 1.0000x reference)
//
#include <hip/hip_runtime.h>
#include <math.h>

#define NB 8
#define NV 100
#define LQ 128
#define NKG 923
#define NT 1024
#define DV 2048
#define DK 300
#define DH 1024
#define NH 8
#define DHD 128
#define NLAYERS 3

// ---------------- block reduce helpers (blockDim.x == 256) ----------------
__device__ __forceinline__ float block_reduce_sum(float v, float* red) {
    int tid = threadIdx.x;
    red[tid] = v; __syncthreads();
    for (int s = 128; s > 0; s >>= 1) {
        if (tid < s) red[tid] += red[tid + s];
        __syncthreads();
    }
    float r = red[0]; __syncthreads();
    return r;
}
__device__ __forceinline__ float block_reduce_max(float v, float* red) {
    int tid = threadIdx.x;
    red[tid] = v; __syncthreads();
    for (int s = 128; s > 0; s >>= 1) {
        if (tid < s) red[tid] = fmaxf(red[tid], red[tid + s]);
        __syncthreads();
    }
    float r = red[0]; __syncthreads();
    return r;
}

// ---------------- GEMM: C[M,N] = A[M,K] @ W[K,N] + bias[N] ----------------
// 64x64 tile, BK=16, 256 threads, 4x4 per thread. N must be a multiple of 64.
__global__ __launch_bounds__(256) void gemm_bias(
    const float* __restrict__ A, const float* __restrict__ W,
    const float* __restrict__ bias, float* __restrict__ C,
    int M, int N, int K)
{
    __shared__ float As[16][64];
    __shared__ float Ws[16][64];
    int tid = threadIdx.x;
    int tx = tid & 15, ty = tid >> 4;
    int row0 = blockIdx.y * 64, col0 = blockIdx.x * 64;
    float acc[4][4] = {};
    for (int k0 = 0; k0 < K; k0 += 16) {
        // A tile: 64 rows x 16 k
        {
            int r = tid >> 2;
            int kk = (tid & 3) * 4;
            int grow = row0 + r;
            float x0 = 0.f, x1 = 0.f, x2 = 0.f, x3 = 0.f;
            if (grow < M) {
                const float* src = A + (size_t)grow * K + k0 + kk;
                if (k0 + kk + 0 < K) x0 = src[0];
                if (k0 + kk + 1 < K) x1 = src[1];
                if (k0 + kk + 2 < K) x2 = src[2];
                if (k0 + kk + 3 < K) x3 = src[3];
            }
            As[kk + 0][r] = x0; As[kk + 1][r] = x1;
            As[kk + 2][r] = x2; As[kk + 3][r] = x3;
        }
        // W tile: 16 k x 64 n
        {
            int kk = tid >> 4;
            int j = (tid & 15) * 4;
            float4 v = make_float4(0.f, 0.f, 0.f, 0.f);
            if (k0 + kk < K)
                v = *(const float4*)(W + (size_t)(k0 + kk) * N + col0 + j);
            *(float4*)&Ws[kk][j] = v;
        }
        __syncthreads();
#pragma unroll
        for (int kk = 0; kk < 16; ++kk) {
            float a0 = As[kk][ty * 4 + 0];
            float a1 = As[kk][ty * 4 + 1];
            float a2 = As[kk][ty * 4 + 2];
            float a3 = As[kk][ty * 4 + 3];
            float4 w = *(float4*)&Ws[kk][tx * 4];
            acc[0][0] += a0 * w.x; acc[0][1] += a0 * w.y; acc[0][2] += a0 * w.z; acc[0][3] += a0 * w.w;
            acc[1][0] += a1 * w.x; acc[1][1] += a1 * w.y; acc[1][2] += a1 * w.z; acc[1][3] += a1 * w.w;
            acc[2][0] += a2 * w.x; acc[2][1] += a2 * w.y; acc[2][2] += a2 * w.z; acc[2][3] += a2 * w.w;
            acc[3][0] += a3 * w.x; acc[3][1] += a3 * w.y; acc[3][2] += a3 * w.z; acc[3][3] += a3 * w.w;
        }
        __syncthreads();
    }
    float4 b4 = *(const float4*)(bias + col0 + tx * 4);
#pragma unroll
    for (int i = 0; i < 4; ++i) {
        int gr = row0 + ty * 4 + i;
        if (gr < M) {
            float4 o;
            o.x = acc[i][0] + b4.x; o.y = acc[i][1] + b4.y;
            o.z = acc[i][2] + b4.z; o.w = acc[i][3] + b4.w;
            *(float4*)(C + (size_t)gr * N + col0 + tx * 4) = o;
        }
    }
}

// ---------------- LayerNorm + scatter into x ----------------
// row r of src -> x row (b*NT + node_off + n), b=r/npb, n=r%npb
__global__ __launch_bounds__(256) void ln_scatter(
    const float* __restrict__ src, float* __restrict__ x,
    const float* __restrict__ g, const float* __restrict__ bta,
    int rows, int npb, int node_off)
{
    __shared__ float red[256];
    int r = blockIdx.x;
    if (r >= rows) return;
    int tid = threadIdx.x;
    int b = r / npb, n = r % npb;
    float4 v = *(const float4*)(src + (size_t)r * DH + tid * 4);
    float s = v.x + v.y + v.z + v.w;
    float sq = v.x * v.x + v.y * v.y + v.z * v.z + v.w * v.w;
    float tot = block_reduce_sum(s, red);
    float totsq = block_reduce_sum(sq, red);
    float mean = tot * (1.0f / DH);
    float var = totsq * (1.0f / DH) - mean * mean;
    float rstd = 1.0f / sqrtf(var + 1e-5f);
    float4 gv = *(const float4*)(g + tid * 4);
    float4 bv = *(const float4*)(bta + tid * 4);
    float4 o;
    o.x = (v.x - mean) * rstd * gv.x + bv.x;
    o.y = (v.y - mean) * rstd * gv.y + bv.y;
    o.z = (v.z - mean) * rstd * gv.z + bv.z;
    o.w = (v.w - mean) * rstd * gv.w + bv.w;
    *(float4*)(x + ((size_t)(b * NT + node_off + n)) * DH + tid * 4) = o;
}

// ---------------- residual + LayerNorm in-place on x ----------------
__global__ __launch_bounds__(256) void ln_residual(
    float* __restrict__ x, const float* __restrict__ o,
    const float* __restrict__ g, const float* __restrict__ bta)
{
    __shared__ float red[256];
    int r = blockIdx.x;
    int tid = threadIdx.x;
    float* xr = x + (size_t)r * DH;
    float4 xv = *(float4*)(xr + tid * 4);
    float4 ov = *(const float4*)(o + (size_t)r * DH + tid * 4);
    float v0 = xv.x + ov.x, v1 = xv.y + ov.y, v2 = xv.z + ov.z, v3 = xv.w + ov.w;
    float s = v0 + v1 + v2 + v3;
    float sq = v0 * v0 + v1 * v1 + v2 * v2 + v3 * v3;
    float tot = block_reduce_sum(s, red);
    float totsq = block_reduce_sum(sq, red);
    float mean = tot * (1.0f / DH);
    float var = totsq * (1.0f / DH) - mean * mean;
    float rstd = 1.0f / sqrtf(var + 1e-5f);
    float4 gv = *(const float4*)(g + tid * 4);
    float4 bv = *(const float4*)(bta + tid * 4);
    float4 out;
    out.x = (v0 - mean) * rstd * gv.x + bv.x;
    out.y = (v1 - mean) * rstd * gv.y + bv.y;
    out.z = (v2 - mean) * rstd * gv.z + bv.z;
    out.w = (v3 - mean) * rstd * gv.w + bv.w;
    *(float4*)(xr + tid * 4) = out;
}

// ---------------- text: masked mean pool of token embeddings ----------------
__global__ __launch_bounds__(256) void pool_kernel(
    const float* __restrict__ tok_emb, const int* __restrict__ ids,
    const int* __restrict__ amask, float* __restrict__ pooled)
{
    int b = blockIdx.x;
    int tid = threadIdx.x;
    float a0 = 0, a1 = 0, a2 = 0, a3 = 0;
    float denom = 0;
    for (int l = 0; l < LQ; ++l) {
        int id = ids[b * LQ + l];
        float m = (float)amask[b * LQ + l];
        denom += m;
        float4 e = *(const float4*)(tok_emb + (size_t)id * DH + tid * 4);
        a0 += m * e.x; a1 += m * e.y; a2 += m * e.z; a3 += m * e.w;
    }
    float inv = 1.0f / fmaxf(denom, 1.0f);
    float4 o = make_float4(a0 * inv, a1 * inv, a2 * inv, a3 * inv);
    *(float4*)(pooled + b * DH + tid * 4) = o;
}

// ---------------- add type embeddings ----------------
__global__ __launch_bounds__(256) void type_add(
    float* __restrict__ x, const int* __restrict__ types,
    const float* __restrict__ type_emb)
{
    int r = blockIdx.x;      // b*NT + n
    int tid = threadIdx.x;
    int ty = types[r];
    float4 xv = *(float4*)(x + (size_t)r * DH + tid * 4);
    float4 tv = *(const float4*)(type_emb + (size_t)ty * DH + tid * 4);
    xv.x += tv.x; xv.y += tv.y; xv.z += tv.z; xv.w += tv.w;
    *(float4*)(x + (size_t)r * DH + tid * 4) = xv;
}

// ---------------- GAT: s/t head scores, one wave per node row ----------------
// s,t stored as [B, H, NT]
__global__ __launch_bounds__(64) void st_kernel(
    const float* __restrict__ hbuf, const float* __restrict__ asrc,
    const float* __restrict__ adst, float* __restrict__ s, float* __restrict__ t)
{
    int r = blockIdx.x;          // b*NT + n
    int lane = threadIdx.x;
    int b = r >> 10, n = r & 1023;
    const float* hrow = hbuf + (size_t)r * DH;
    for (int h = 0; h < NH; ++h) {
        float2 v = *(const float2*)(hrow + h * DHD + lane * 2);
        float2 s2 = *(const float2*)(asrc + h * DHD + lane * 2);
        float2 t2 = *(const float2*)(adst + h * DHD + lane * 2);
        float ps = v.x * s2.x + v.y * s2.y;
        float pt = v.x * t2.x + v.y * t2.y;
        for (int off = 32; off > 0; off >>= 1) {
            ps += __shfl_down(ps, off, 64);
            pt += __shfl_down(pt, off, 64);
        }
        if (lane == 0) {
            s[(size_t)(b * NH + h) * NT + n] = ps;
            t[(size_t)(b * NH + h) * NT + n] = pt;
        }
    }
}

// ---------------- GAT: masked softmax row stats (max m, inv sum) ----------------
__global__ __launch_bounds__(256) void stats_kernel(
    const int* __restrict__ adj, const float* __restrict__ s,
    const float* __restrict__ t, float* __restrict__ mbuf, float* __restrict__ lbuf)
{
    __shared__ float red[256];
    __shared__ unsigned char mrow[NT];
    int bi = blockIdx.x;           // b*NT + i
    int b = bi >> 10, i = bi & 1023;
    int tid = threadIdx.x;
    const int* arow = adj + (size_t)bi * NT;
    for (int j = tid; j < NT; j += 256) mrow[j] = (unsigned char)(arow[j] > 0);
    __syncthreads();
    for (int h = 0; h < NH; ++h) {
        const float* tp = t + (size_t)(b * NH + h) * NT;
        float si = s[(size_t)(b * NH + h) * NT + i];
        float vals[4];
        float mx = -3e38f;
#pragma unroll
        for (int k = 0; k < 4; ++k) {
            int j = tid + k * 256;
            float v = si + tp[j];
            v = v > 0.f ? v : 0.2f * v;
            v = mrow[j] ? v : -1e9f;
            vals[k] = v;
            mx = fmaxf(mx, v);
        }
        float m = block_reduce_max(mx, red);
        float ls = 0.f;
#pragma unroll
        for (int k = 0; k < 4; ++k) ls += __expf(vals[k] - m);
        float tot = block_reduce_sum(ls, red);
        if (tid == 0) {
            mbuf[(size_t)(b * NH + h) * NT + i] = m;
            lbuf[(size_t)(b * NH + h) * NT + i] = 1.0f / tot;
        }
        __syncthreads();
    }
}

// ---------------- GAT: attention aggregation out[b,i,h,:] = sum_j a_ij h[b,j,h,:] ----
// grid (NT/64, H, B), 256 threads; A-tile recomputed on the fly.
__global__ __launch_bounds__(256) void agg_kernel(
    const float* __restrict__ hbuf, const int* __restrict__ adj,
    const float* __restrict__ s, const float* __restrict__ t,
    const float* __restrict__ mbuf, const float* __restrict__ lbuf,
    float* __restrict__ obuf)
{
    __shared__ float vt[64][128];
    __shared__ float at[64][64];
    __shared__ float sv[64], mv[64], lv[64], tv[64];
    int i0 = blockIdx.x * 64;
    int h = blockIdx.y;
    int b = blockIdx.z;
    int tid = threadIdx.x;
    if (tid < 64) {
        size_t idx = (size_t)(b * NH + h) * NT + i0 + tid;
        sv[tid] = s[idx]; mv[tid] = mbuf[idx]; lv[tid] = lbuf[idx];
    }
    float acc[8][4] = {};
    int tx = tid & 31, ty = tid >> 5;
    for (int j0 = 0; j0 < NT; j0 += 64) {
        __syncthreads();   // protect LDS reuse from previous iteration
        if (tid < 64) tv[tid] = t[(size_t)(b * NH + h) * NT + j0 + tid];
#pragma unroll
        for (int it = 0; it < 8; ++it) {
            int f = tid + it * 256;      // 0..2047 float4 slots
            int jj = f >> 5;
            int d4 = f & 31;
            *(float4*)&vt[jj][d4 * 4] =
                *(const float4*)(hbuf + ((size_t)(b * NT + j0 + jj)) * DH + h * DHD + d4 * 4);
        }
        __syncthreads();
#pragma unroll
        for (int k = 0; k < 16; ++k) {
            int e = tid + k * 256;       // 0..4095
            int ii = e >> 6, jj = e & 63;
            int msk = adj[((size_t)(b * NT + i0 + ii)) * NT + j0 + jj];
            float v = sv[ii] + tv[jj];
            v = v > 0.f ? v : 0.2f * v;
            at[ii][jj] = (msk > 0) ? __expf(v - mv[ii]) * lv[ii] : 0.f;
        }
        __syncthreads();
#pragma unroll 4
        for (int jj = 0; jj < 64; ++jj) {
            float4 v = *(float4*)&vt[jj][tx * 4];
#pragma unroll
            for (int r = 0; r < 8; ++r) {
                float a = at[ty * 8 + r][jj];
                acc[r][0] += a * v.x; acc[r][1] += a * v.y;
                acc[r][2] += a * v.z; acc[r][3] += a * v.w;
            }
        }
    }
#pragma unroll
    for (int r = 0; r < 8; ++r) {
        int i = i0 + ty * 8 + r;
        float4 o = make_float4(acc[r][0], acc[r][1], acc[r][2], acc[r][3]);
        *(float4*)(obuf + ((size_t)(b * NT + i)) * DH + h * DHD + tx * 4) = o;
    }
}

// ---------------- readout scores: one wave per node ----------------
__global__ __launch_bounds__(64) void score_kernel(
    const float* __restrict__ x, const float* __restrict__ rW,
    const float* __restrict__ rb, float* __restrict__ scores)
{
    int r = blockIdx.x;
    int lane = threadIdx.x;
    const float* xr = x + (size_t)r * DH;
    float acc = 0.f;
#pragma unroll
    for (int k = 0; k < 4; ++k) {
        float4 xv = *(const float4*)(xr + lane * 16 + k * 4);
        float4 wv = *(const float4*)(rW + lane * 16 + k * 4);
        acc += xv.x * wv.x + xv.y * wv.y + xv.z * wv.z + xv.w * wv.w;
    }
    for (int off = 32; off > 0; off >>= 1) acc += __shfl_down(acc, off, 64);
    if (lane == 0) scores[r] = acc + rb[0];
}

// ---------------- per-batch softmax over node scores (in place) ----------------
__global__ __launch_bounds__(256) void softmax_w(float* __restrict__ scores)
{
    __shared__ float red[256];
    int b = blockIdx.x;
    int tid = threadIdx.x;
    float* sr = scores + (size_t)b * NT;
    float v[4];
    float mx = -3e38f;
#pragma unroll
    for (int k = 0; k < 4; ++k) { v[k] = sr[tid + k * 256]; mx = fmaxf(mx, v[k]); }
    float m = block_reduce_max(mx, red);
    float ls = 0.f;
#pragma unroll
    for (int k = 0; k < 4; ++k) { v[k] = expf(v[k] - m); ls += v[k]; }
    float tot = block_reduce_sum(ls, red);
    float inv = 1.0f / tot;
#pragma unroll
    for (int k = 0; k < 4; ++k) sr[tid + k * 256] = v[k] * inv;
}

// ---------------- weighted pool partials: g_part[b,p,:] over node range ------
__global__ __launch_bounds__(256) void pool_part(
    const float* __restrict__ x, const float* __restrict__ w,
    float* __restrict__ gpart)
{
    int p = blockIdx.x;   // 0..7
    int b = blockIdx.y;
    int tid = threadIdx.x;
    float a0 = 0, a1 = 0, a2 = 0, a3 = 0;
    for (int n = p * 128; n < (p + 1) * 128; ++n) {
        float wv = w[(size_t)b * NT + n];
        float4 xv = *(const float4*)(x + ((size_t)(b * NT + n)) * DH + tid * 4);
        a0 += wv * xv.x; a1 += wv * xv.y; a2 += wv * xv.z; a3 += wv * xv.w;
    }
    float4 o = make_float4(a0, a1, a2, a3);
    *(float4*)(gpart + ((size_t)(b * 8 + p)) * DH + tid * 4) = o;
}

// ---------------- final candidate scorer ----------------
__global__ __launch_bounds__(256) void scorer_kernel(
    const float* __restrict__ gpart, const float* __restrict__ W1,
    const float* __restrict__ b1, const float* __restrict__ W2,
    const float* __restrict__ b2, float* __restrict__ out)
{
    __shared__ float gsh[DH];
    __shared__ float red[256];
    int b = blockIdx.x;
    int tid = threadIdx.x;
#pragma unroll
    for (int c = 0; c < 4; ++c) {
        int d = tid + c * 256;
        float gv = 0.f;
        for (int p = 0; p < 8; ++p) gv += gpart[((size_t)(b * 8 + p)) * DH + d];
        gsh[d] = gv;
    }
    __syncthreads();
    float acc[4] = {};
    for (int d = 0; d < DH; ++d) {
        float gv = gsh[d];
        const float* wr = W1 + (size_t)d * DH;
#pragma unroll
        for (int c = 0; c < 4; ++c) acc[c] += gv * wr[tid + c * 256];
    }
    float part = 0.f;
#pragma unroll
    for (int c = 0; c < 4; ++c) {
        int k = tid + c * 256;
        float u = acc[c] + b1[k];
        float inner = 0.7978845608028654f * (u + 0.044715f * u * u * u);
        float gel = 0.5f * u * (1.0f + tanhf(inner));
        part += gel * W2[k];
    }
    float tot = block_reduce_sum(part, red);
    if (tid == 0) out[b] = tot + b2[0];
}

// ---------------- launch ----------------
extern "C" void kernel_launch(void* const* d_in, const int* in_sizes, int n_in,
                              void* d_out, int out_size, void* d_ws, size_t ws_size,
                              hipStream_t stream)
{
    const float* visual   = (const float*)d_in[0];
    const int*   q_ids    = (const int*)d_in[1];
    const int*   q_mask   = (const int*)d_in[2];
    const float* kg_feat  = (const float*)d_in[3];
    const int*   adj      = (const int*)d_in[4];
    const int*   ntypes   = (const int*)d_in[5];
    const float* vis_W    = (const float*)d_in[6];
    const float* vis_b    = (const float*)d_in[7];
    const float* vis_lng  = (const float*)d_in[8];
    const float* vis_lnb  = (const float*)d_in[9];
    const float* tok_emb  = (const float*)d_in[10];
    const float* q_W      = (const float*)d_in[11];
    const float* q_b      = (const float*)d_in[12];
    const float* q_lng    = (const float*)d_in[13];
    const float* q_lnb    = (const float*)d_in[14];
    const float* kg_W     = (const float*)d_in[15];
    const float* kg_b     = (const float*)d_in[16];
    const float* kg_lng   = (const float*)d_in[17];
    const float* kg_lnb   = (const float*)d_in[18];
    const float* type_emb = (const float*)d_in[19];
    const float* gat_W    = (const float*)d_in[20];
    const float* gat_b    = (const float*)d_in[21];
    const float* a_src    = (const float*)d_in[22];
    const float* a_dst    = (const float*)d_in[23];
    const float* gat_lng  = (const float*)d_in[24];
    const float* gat_lnb  = (const float*)d_in[25];
    const float* read_W   = (const float*)d_in[26];
    const float* read_b   = (const float*)d_in[27];
    const float* cs_W1    = (const float*)d_in[28];
    const float* cs_b1    = (const float*)d_in[29];
    const float* cs_W2    = (const float*)d_in[30];
    const float* cs_b2    = (const float*)d_in[31];
    float* out = (float*)d_out;

    float* ws = (float*)d_ws;
    const size_t NROW = (size_t)NB * NT;              // 8192
    float* x      = ws;                               // 8M floats
    float* hbuf   = x + NROW * DH;                    // 8M
    float* obuf   = hbuf + NROW * DH;                 // 8M (also GEMM temp)
    float* sbuf   = obuf + NROW * DH;                 // 64K
    float* tbuf   = sbuf + NB * NH * NT;              // 64K
    float* mbuf   = tbuf + NB * NH * NT;              // 64K
    float* lbuf   = mbuf + NB * NH * NT;              // 64K
    float* pooled = lbuf + NB * NH * NT;              // 8K
    float* scores = pooled + NB * DH;                 // 8K
    float* gpart  = scores + NROW;                    // 64K

    // 1. visual projection + LN -> x[:, 0:100]
    gemm_bias<<<dim3(16, (NB * NV + 63) / 64), 256, 0, stream>>>(
        visual, vis_W, vis_b, obuf, NB * NV, DH, DV);
    ln_scatter<<<NB * NV, 256, 0, stream>>>(obuf, x, vis_lng, vis_lnb, NB * NV, NV, 0);

    // 2. text pool + proj + LN -> x[:, 100]
    pool_kernel<<<NB, 256, 0, stream>>>(tok_emb, q_ids, q_mask, pooled);
    gemm_bias<<<dim3(16, 1), 256, 0, stream>>>(pooled, q_W, q_b, obuf, NB, DH, DH);
    ln_scatter<<<NB, 256, 0, stream>>>(obuf, x, q_lng, q_lnb, NB, 1, NV);

    // 3. KG projection + LN -> x[:, 101:1024]
    gemm_bias<<<dim3(16, (NB * NKG + 63) / 64), 256, 0, stream>>>(
        kg_feat, kg_W, kg_b, obuf, NB * NKG, DH, DK);
    ln_scatter<<<NB * NKG, 256, 0, stream>>>(obuf, x, kg_lng, kg_lnb, NB * NKG, NKG, NV + 1);

    // 4. + type embeddings
    type_add<<<NB * NT, 256, 0, stream>>>(x, ntypes, type_emb);

    // 5. GAT layers
    for (int l = 0; l < NLAYERS; ++l) {
        const float* Wl  = gat_W + (size_t)l * DH * DH;
        const float* bl  = gat_b + (size_t)l * DH;
        const float* asl = a_src + (size_t)l * NH * DHD;
        const float* adl = a_dst + (size_t)l * NH * DHD;
        gemm_bias<<<dim3(16, 128), 256, 0, stream>>>(x, Wl, bl, hbuf, NB * NT, DH, DH);
        st_kernel<<<NB * NT, 64, 0, stream>>>(hbuf, asl, adl, sbuf, tbuf);
        stats_kernel<<<NB * NT, 256, 0, stream>>>(adj, sbuf, tbuf, mbuf, lbuf);
        agg_kernel<<<dim3(16, NH, NB), 256, 0, stream>>>(hbuf, adj, sbuf, tbuf, mbuf, lbuf, obuf);
        ln_residual<<<NB * NT, 256, 0, stream>>>(x, obuf,
            gat_lng + (size_t)l * DH, gat_lnb + (size_t)l * DH);
    }

    // 6. readout + scorer
    score_kernel<<<NB * NT, 64, 0, stream>>>(x, read_W, read_b, scores);
    softmax_w<<<NB, 256, 0, stream>>>(scores);
    pool_part<<<dim3(8, NB), 256, 0, stream>>>(x, scores, gpart);
    scorer_kernel<<<NB, 256, 0, stream>>>(gpart, cs_W1, cs_b1, cs_W2, cs_b2, out);
}

// Round 2
// 2871.700 us; speedup vs baseline: 1.1472x; 1.1472x over previous
//
#include <hip/hip_runtime.h>
#include <math.h>

#define NB 8
#define NV 100
#define LQ 128
#define NKG 923
#define NT 1024
#define DV 2048
#define DK 300
#define DH 1024
#define NH 8
#define DHD 128
#define NLAYERS 3

// ---------------- block reduce helpers (blockDim.x == 256) ----------------
__device__ __forceinline__ float block_reduce_sum(float v, float* red) {
    int tid = threadIdx.x;
    red[tid] = v; __syncthreads();
    for (int s = 128; s > 0; s >>= 1) {
        if (tid < s) red[tid] += red[tid + s];
        __syncthreads();
    }
    float r = red[0]; __syncthreads();
    return r;
}
__device__ __forceinline__ float block_reduce_max(float v, float* red) {
    int tid = threadIdx.x;
    red[tid] = v; __syncthreads();
    for (int s = 128; s > 0; s >>= 1) {
        if (tid < s) red[tid] = fmaxf(red[tid], red[tid + s]);
        __syncthreads();
    }
    float r = red[0]; __syncthreads();
    return r;
}

// ---------------- GEMM: C[M,N] = A[M,K] @ W[K,N] + bias[N] ----------------
// 128x128 tile, BK=16, 256 threads, 8x8 per thread. N must be multiple of 128.
__global__ __launch_bounds__(256) void gemm_bias(
    const float* __restrict__ A, const float* __restrict__ W,
    const float* __restrict__ bias, float* __restrict__ C,
    int M, int N, int K)
{
    __shared__ float As[16][132];   // [kk][m], pad 132 (16B-aligned rows, 2-way write alias = free)
    __shared__ float Ws[16][128];   // [kk][n]
    int tid = threadIdx.x;
    int tx = tid & 15;              // n-group: n = tx*8 .. +7
    int ty = tid >> 4;              // m-group: m = ty*8 .. +7
    int row0 = blockIdx.y * 128, col0 = blockIdx.x * 128;
    float acc[8][8] = {};
    for (int k0 = 0; k0 < K; k0 += 16) {
        // stage A tile: 128 rows x 16 k (transposed into As[kk][m])
#pragma unroll
        for (int s = 0; s < 2; ++s) {
            int f = tid + s * 256;
            int r = f >> 2, c4 = (f & 3) * 4;
            int grow = row0 + r;
            float4 v = make_float4(0.f, 0.f, 0.f, 0.f);
            if (grow < M) {
                const float* src = A + (size_t)grow * K;
                if (k0 + c4 + 4 <= K) {
                    v = *(const float4*)(src + k0 + c4);
                } else {
                    if (k0 + c4 + 0 < K) v.x = src[k0 + c4 + 0];
                    if (k0 + c4 + 1 < K) v.y = src[k0 + c4 + 1];
                    if (k0 + c4 + 2 < K) v.z = src[k0 + c4 + 2];
                    if (k0 + c4 + 3 < K) v.w = src[k0 + c4 + 3];
                }
            }
            As[c4 + 0][r] = v.x; As[c4 + 1][r] = v.y;
            As[c4 + 2][r] = v.z; As[c4 + 3][r] = v.w;
        }
        // stage W tile: 16 k x 128 n
#pragma unroll
        for (int s = 0; s < 2; ++s) {
            int f = tid + s * 256;
            int kk = f >> 5, n4 = (f & 31) * 4;
            float4 v = make_float4(0.f, 0.f, 0.f, 0.f);
            if (k0 + kk < K)
                v = *(const float4*)(W + (size_t)(k0 + kk) * N + col0 + n4);
            *(float4*)&Ws[kk][n4] = v;
        }
        __syncthreads();
#pragma unroll
        for (int kk = 0; kk < 16; ++kk) {
            float4 a0 = *(float4*)&As[kk][ty * 8];
            float4 a1 = *(float4*)&As[kk][ty * 8 + 4];
            float4 w0 = *(float4*)&Ws[kk][tx * 8];
            float4 w1 = *(float4*)&Ws[kk][tx * 8 + 4];
            float am[8] = {a0.x, a0.y, a0.z, a0.w, a1.x, a1.y, a1.z, a1.w};
            float wn[8] = {w0.x, w0.y, w0.z, w0.w, w1.x, w1.y, w1.z, w1.w};
#pragma unroll
            for (int i = 0; i < 8; ++i)
#pragma unroll
                for (int j = 0; j < 8; ++j)
                    acc[i][j] += am[i] * wn[j];
        }
        __syncthreads();
    }
    float4 b0 = *(const float4*)(bias + col0 + tx * 8);
    float4 b1 = *(const float4*)(bias + col0 + tx * 8 + 4);
#pragma unroll
    for (int i = 0; i < 8; ++i) {
        int gr = row0 + ty * 8 + i;
        if (gr < M) {
            float4 o0, o1;
            o0.x = acc[i][0] + b0.x; o0.y = acc[i][1] + b0.y;
            o0.z = acc[i][2] + b0.z; o0.w = acc[i][3] + b0.w;
            o1.x = acc[i][4] + b1.x; o1.y = acc[i][5] + b1.y;
            o1.z = acc[i][6] + b1.z; o1.w = acc[i][7] + b1.w;
            *(float4*)(C + (size_t)gr * N + col0 + tx * 8) = o0;
            *(float4*)(C + (size_t)gr * N + col0 + tx * 8 + 4) = o1;
        }
    }
}

// ---------------- LayerNorm + scatter into x ----------------
__global__ __launch_bounds__(256) void ln_scatter(
    const float* __restrict__ src, float* __restrict__ x,
    const float* __restrict__ g, const float* __restrict__ bta,
    int rows, int npb, int node_off)
{
    __shared__ float red[256];
    int r = blockIdx.x;
    if (r >= rows) return;
    int tid = threadIdx.x;
    int b = r / npb, n = r % npb;
    float4 v = *(const float4*)(src + (size_t)r * DH + tid * 4);
    float s = v.x + v.y + v.z + v.w;
    float sq = v.x * v.x + v.y * v.y + v.z * v.z + v.w * v.w;
    float tot = block_reduce_sum(s, red);
    float totsq = block_reduce_sum(sq, red);
    float mean = tot * (1.0f / DH);
    float var = totsq * (1.0f / DH) - mean * mean;
    float rstd = 1.0f / sqrtf(var + 1e-5f);
    float4 gv = *(const float4*)(g + tid * 4);
    float4 bv = *(const float4*)(bta + tid * 4);
    float4 o;
    o.x = (v.x - mean) * rstd * gv.x + bv.x;
    o.y = (v.y - mean) * rstd * gv.y + bv.y;
    o.z = (v.z - mean) * rstd * gv.z + bv.z;
    o.w = (v.w - mean) * rstd * gv.w + bv.w;
    *(float4*)(x + ((size_t)(b * NT + node_off + n)) * DH + tid * 4) = o;
}

// ---------------- residual + LayerNorm in-place on x ----------------
__global__ __launch_bounds__(256) void ln_residual(
    float* __restrict__ x, const float* __restrict__ o,
    const float* __restrict__ g, const float* __restrict__ bta)
{
    __shared__ float red[256];
    int r = blockIdx.x;
    int tid = threadIdx.x;
    float* xr = x + (size_t)r * DH;
    float4 xv = *(float4*)(xr + tid * 4);
    float4 ov = *(const float4*)(o + (size_t)r * DH + tid * 4);
    float v0 = xv.x + ov.x, v1 = xv.y + ov.y, v2 = xv.z + ov.z, v3 = xv.w + ov.w;
    float s = v0 + v1 + v2 + v3;
    float sq = v0 * v0 + v1 * v1 + v2 * v2 + v3 * v3;
    float tot = block_reduce_sum(s, red);
    float totsq = block_reduce_sum(sq, red);
    float mean = tot * (1.0f / DH);
    float var = totsq * (1.0f / DH) - mean * mean;
    float rstd = 1.0f / sqrtf(var + 1e-5f);
    float4 gv = *(const float4*)(g + tid * 4);
    float4 bv = *(const float4*)(bta + tid * 4);
    float4 out;
    out.x = (v0 - mean) * rstd * gv.x + bv.x;
    out.y = (v1 - mean) * rstd * gv.y + bv.y;
    out.z = (v2 - mean) * rstd * gv.z + bv.z;
    out.w = (v3 - mean) * rstd * gv.w + bv.w;
    *(float4*)(xr + tid * 4) = out;
}

// ---------------- text: masked mean pool of token embeddings ----------------
__global__ __launch_bounds__(256) void pool_kernel(
    const float* __restrict__ tok_emb, const int* __restrict__ ids,
    const int* __restrict__ amask, float* __restrict__ pooled)
{
    int b = blockIdx.x;
    int tid = threadIdx.x;
    float a0 = 0, a1 = 0, a2 = 0, a3 = 0;
    float denom = 0;
    for (int l = 0; l < LQ; ++l) {
        int id = ids[b * LQ + l];
        float m = (float)amask[b * LQ + l];
        denom += m;
        float4 e = *(const float4*)(tok_emb + (size_t)id * DH + tid * 4);
        a0 += m * e.x; a1 += m * e.y; a2 += m * e.z; a3 += m * e.w;
    }
    float inv = 1.0f / fmaxf(denom, 1.0f);
    float4 o = make_float4(a0 * inv, a1 * inv, a2 * inv, a3 * inv);
    *(float4*)(pooled + b * DH + tid * 4) = o;
}

// ---------------- add type embeddings ----------------
__global__ __launch_bounds__(256) void type_add(
    float* __restrict__ x, const int* __restrict__ types,
    const float* __restrict__ type_emb)
{
    int r = blockIdx.x;
    int tid = threadIdx.x;
    int ty = types[r];
    float4 xv = *(float4*)(x + (size_t)r * DH + tid * 4);
    float4 tv = *(const float4*)(type_emb + (size_t)ty * DH + tid * 4);
    xv.x += tv.x; xv.y += tv.y; xv.z += tv.z; xv.w += tv.w;
    *(float4*)(x + (size_t)r * DH + tid * 4) = xv;
}

// ---------------- GAT: s/t head scores, one wave per node row ----------------
__global__ __launch_bounds__(64) void st_kernel(
    const float* __restrict__ hbuf, const float* __restrict__ asrc,
    const float* __restrict__ adst, float* __restrict__ s, float* __restrict__ t)
{
    int r = blockIdx.x;
    int lane = threadIdx.x;
    int b = r >> 10, n = r & 1023;
    const float* hrow = hbuf + (size_t)r * DH;
    for (int h = 0; h < NH; ++h) {
        float2 v = *(const float2*)(hrow + h * DHD + lane * 2);
        float2 s2 = *(const float2*)(asrc + h * DHD + lane * 2);
        float2 t2 = *(const float2*)(adst + h * DHD + lane * 2);
        float ps = v.x * s2.x + v.y * s2.y;
        float pt = v.x * t2.x + v.y * t2.y;
        for (int off = 32; off > 0; off >>= 1) {
            ps += __shfl_down(ps, off, 64);
            pt += __shfl_down(pt, off, 64);
        }
        if (lane == 0) {
            s[(size_t)(b * NH + h) * NT + n] = ps;
            t[(size_t)(b * NH + h) * NT + n] = pt;
        }
    }
}

// ---------------- GAT: masked softmax row stats (max m, inv sum) ----------------
__global__ __launch_bounds__(256) void stats_kernel(
    const int* __restrict__ adj, const float* __restrict__ s,
    const float* __restrict__ t, float* __restrict__ mbuf, float* __restrict__ lbuf)
{
    __shared__ float red[256];
    __shared__ unsigned char mrow[NT];
    int bi = blockIdx.x;
    int b = bi >> 10, i = bi & 1023;
    int tid = threadIdx.x;
    const int* arow = adj + (size_t)bi * NT;
    for (int j = tid; j < NT; j += 256) mrow[j] = (unsigned char)(arow[j] > 0);
    __syncthreads();
    for (int h = 0; h < NH; ++h) {
        const float* tp = t + (size_t)(b * NH + h) * NT;
        float si = s[(size_t)(b * NH + h) * NT + i];
        float vals[4];
        float mx = -3e38f;
#pragma unroll
        for (int k = 0; k < 4; ++k) {
            int j = tid + k * 256;
            float v = si + tp[j];
            v = v > 0.f ? v : 0.2f * v;
            v = mrow[j] ? v : -1e9f;
            vals[k] = v;
            mx = fmaxf(mx, v);
        }
        float m = block_reduce_max(mx, red);
        float ls = 0.f;
#pragma unroll
        for (int k = 0; k < 4; ++k) ls += __expf(vals[k] - m);
        float tot = block_reduce_sum(ls, red);
        if (tid == 0) {
            mbuf[(size_t)(b * NH + h) * NT + i] = m;
            lbuf[(size_t)(b * NH + h) * NT + i] = 1.0f / tot;
        }
        __syncthreads();
    }
}

// ---------------- GAT: attention aggregation out[b,i,h,:] = sum_j a_ij h[b,j,h,:] ----
// grid (16, H, B), 256 threads. Per thread: 4 i-rows x 8 d.
// Inner loop: 12 ds_read_b128 per 128 FMAs (was 36 mostly-scalar LDS / 128 FMA).
__global__ __launch_bounds__(256) void agg_kernel(
    const float* __restrict__ hbuf, const int* __restrict__ adj,
    const float* __restrict__ s, const float* __restrict__ t,
    const float* __restrict__ mbuf, const float* __restrict__ lbuf,
    float* __restrict__ obuf)
{
    __shared__ float vt[64][128];     // v tile [jj][d]
    __shared__ float at[64][68];      // attention tile [ii][jj], pad 68 keeps 16B align
    __shared__ float sv[64], mv[64], lv[64], tv[64];
    int i0 = blockIdx.x * 64;
    int h = blockIdx.y;
    int b = blockIdx.z;
    int tid = threadIdx.x;
    int tx = tid & 15;    // d-group: d = tx*8 .. +7
    int ty = tid >> 4;    // i-group: i = ty*4 .. +3
    if (tid < 64) {
        size_t idx = (size_t)(b * NH + h) * NT + i0 + tid;
        sv[tid] = s[idx]; mv[tid] = mbuf[idx]; lv[tid] = lbuf[idx];
    }
    float acc[4][8] = {};
    const float* tptr = t + (size_t)(b * NH + h) * NT;
    for (int j0 = 0; j0 < NT; j0 += 64) {
        __syncthreads();     // protect LDS reuse from previous iteration
        if (tid < 64) tv[tid] = tptr[j0 + tid];
        // stage v tile: 8192 floats = 2048 float4, 8 per thread
#pragma unroll
        for (int it = 0; it < 8; ++it) {
            int f = tid + it * 256;
            int jj = f >> 5, d4 = (f & 31) * 4;
            *(float4*)&vt[jj][d4] =
                *(const float4*)(hbuf + ((size_t)(b * NT + j0 + jj)) * DH + h * DHD + d4);
        }
        __syncthreads();
        // at tile: 4096 elems via int4 adj loads, float4 LDS writes
#pragma unroll
        for (int k = 0; k < 4; ++k) {
            int f = tid + k * 256;
            int ii = f >> 4, jq = (f & 15) * 4;
            int4 a4 = *(const int4*)(adj + ((size_t)(b * NT + i0 + ii)) * NT + j0 + jq);
            float svv = sv[ii], mvv = mv[ii], lvv = lv[ii];
            float4 o; float v;
            v = svv + tv[jq + 0]; v = v > 0.f ? v : 0.2f * v; o.x = a4.x > 0 ? __expf(v - mvv) * lvv : 0.f;
            v = svv + tv[jq + 1]; v = v > 0.f ? v : 0.2f * v; o.y = a4.y > 0 ? __expf(v - mvv) * lvv : 0.f;
            v = svv + tv[jq + 2]; v = v > 0.f ? v : 0.2f * v; o.z = a4.z > 0 ? __expf(v - mvv) * lvv : 0.f;
            v = svv + tv[jq + 3]; v = v > 0.f ? v : 0.2f * v; o.w = a4.w > 0 ? __expf(v - mvv) * lvv : 0.f;
            *(float4*)&at[ii][jq] = o;
        }
        __syncthreads();
        // compute: jj unrolled by 4, float4 a-reads along jj
#pragma unroll 4
        for (int jj = 0; jj < 64; jj += 4) {
            float4 av0 = *(float4*)&at[ty * 4 + 0][jj];
            float4 av1 = *(float4*)&at[ty * 4 + 1][jj];
            float4 av2 = *(float4*)&at[ty * 4 + 2][jj];
            float4 av3 = *(float4*)&at[ty * 4 + 3][jj];
            float aq[4][4] = {{av0.x, av0.y, av0.z, av0.w},
                              {av1.x, av1.y, av1.z, av1.w},
                              {av2.x, av2.y, av2.z, av2.w},
                              {av3.x, av3.y, av3.z, av3.w}};
#pragma unroll
            for (int p = 0; p < 4; ++p) {
                float4 v0 = *(float4*)&vt[jj + p][tx * 8];
                float4 v1 = *(float4*)&vt[jj + p][tx * 8 + 4];
                float vd[8] = {v0.x, v0.y, v0.z, v0.w, v1.x, v1.y, v1.z, v1.w};
#pragma unroll
                for (int q = 0; q < 4; ++q) {
                    float a = aq[q][p];
#pragma unroll
                    for (int d = 0; d < 8; ++d) acc[q][d] += a * vd[d];
                }
            }
        }
    }
#pragma unroll
    for (int q = 0; q < 4; ++q) {
        int i = i0 + ty * 4 + q;
        float4 o0 = make_float4(acc[q][0], acc[q][1], acc[q][2], acc[q][3]);
        float4 o1 = make_float4(acc[q][4], acc[q][5], acc[q][6], acc[q][7]);
        float* dst = obuf + ((size_t)(b * NT + i)) * DH + h * DHD + tx * 8;
        *(float4*)dst = o0;
        *(float4*)(dst + 4) = o1;
    }
}

// ---------------- readout scores: one wave per node ----------------
__global__ __launch_bounds__(64) void score_kernel(
    const float* __restrict__ x, const float* __restrict__ rW,
    const float* __restrict__ rb, float* __restrict__ scores)
{
    int r = blockIdx.x;
    int lane = threadIdx.x;
    const float* xr = x + (size_t)r * DH;
    float acc = 0.f;
#pragma unroll
    for (int k = 0; k < 4; ++k) {
        float4 xv = *(const float4*)(xr + lane * 16 + k * 4);
        float4 wv = *(const float4*)(rW + lane * 16 + k * 4);
        acc += xv.x * wv.x + xv.y * wv.y + xv.z * wv.z + xv.w * wv.w;
    }
    for (int off = 32; off > 0; off >>= 1) acc += __shfl_down(acc, off, 64);
    if (lane == 0) scores[r] = acc + rb[0];
}

// ---------------- per-batch softmax over node scores (in place) ----------------
__global__ __launch_bounds__(256) void softmax_w(float* __restrict__ scores)
{
    __shared__ float red[256];
    int b = blockIdx.x;
    int tid = threadIdx.x;
    float* sr = scores + (size_t)b * NT;
    float v[4];
    float mx = -3e38f;
#pragma unroll
    for (int k = 0; k < 4; ++k) { v[k] = sr[tid + k * 256]; mx = fmaxf(mx, v[k]); }
    float m = block_reduce_max(mx, red);
    float ls = 0.f;
#pragma unroll
    for (int k = 0; k < 4; ++k) { v[k] = expf(v[k] - m); ls += v[k]; }
    float tot = block_reduce_sum(ls, red);
    float inv = 1.0f / tot;
#pragma unroll
    for (int k = 0; k < 4; ++k) sr[tid + k * 256] = v[k] * inv;
}

// ---------------- weighted pool partials ----------------
__global__ __launch_bounds__(256) void pool_part(
    const float* __restrict__ x, const float* __restrict__ w,
    float* __restrict__ gpart)
{
    int p = blockIdx.x;
    int b = blockIdx.y;
    int tid = threadIdx.x;
    float a0 = 0, a1 = 0, a2 = 0, a3 = 0;
    for (int n = p * 128; n < (p + 1) * 128; ++n) {
        float wv = w[(size_t)b * NT + n];
        float4 xv = *(const float4*)(x + ((size_t)(b * NT + n)) * DH + tid * 4);
        a0 += wv * xv.x; a1 += wv * xv.y; a2 += wv * xv.z; a3 += wv * xv.w;
    }
    float4 o = make_float4(a0, a1, a2, a3);
    *(float4*)(gpart + ((size_t)(b * 8 + p)) * DH + tid * 4) = o;
}

// ---------------- final candidate scorer ----------------
__global__ __launch_bounds__(256) void scorer_kernel(
    const float* __restrict__ gpart, const float* __restrict__ W1,
    const float* __restrict__ b1, const float* __restrict__ W2,
    const float* __restrict__ b2, float* __restrict__ out)
{
    __shared__ float gsh[DH];
    __shared__ float red[256];
    int b = blockIdx.x;
    int tid = threadIdx.x;
#pragma unroll
    for (int c = 0; c < 4; ++c) {
        int d = tid + c * 256;
        float gv = 0.f;
        for (int p = 0; p < 8; ++p) gv += gpart[((size_t)(b * 8 + p)) * DH + d];
        gsh[d] = gv;
    }
    __syncthreads();
    float acc[4] = {};
    for (int d = 0; d < DH; ++d) {
        float gv = gsh[d];
        const float* wr = W1 + (size_t)d * DH;
#pragma unroll
        for (int c = 0; c < 4; ++c) acc[c] += gv * wr[tid + c * 256];
    }
    float part = 0.f;
#pragma unroll
    for (int c = 0; c < 4; ++c) {
        int k = tid + c * 256;
        float u = acc[c] + b1[k];
        float inner = 0.7978845608028654f * (u + 0.044715f * u * u * u);
        float gel = 0.5f * u * (1.0f + tanhf(inner));
        part += gel * W2[k];
    }
    float tot = block_reduce_sum(part, red);
    if (tid == 0) out[b] = tot + b2[0];
}

// ---------------- launch ----------------
extern "C" void kernel_launch(void* const* d_in, const int* in_sizes, int n_in,
                              void* d_out, int out_size, void* d_ws, size_t ws_size,
                              hipStream_t stream)
{
    const float* visual   = (const float*)d_in[0];
    const int*   q_ids    = (const int*)d_in[1];
    const int*   q_mask   = (const int*)d_in[2];
    const float* kg_feat  = (const float*)d_in[3];
    const int*   adj      = (const int*)d_in[4];
    const int*   ntypes   = (const int*)d_in[5];
    const float* vis_W    = (const float*)d_in[6];
    const float* vis_b    = (const float*)d_in[7];
    const float* vis_lng  = (const float*)d_in[8];
    const float* vis_lnb  = (const float*)d_in[9];
    const float* tok_emb  = (const float*)d_in[10];
    const float* q_W      = (const float*)d_in[11];
    const float* q_b      = (const float*)d_in[12];
    const float* q_lng    = (const float*)d_in[13];
    const float* q_lnb    = (const float*)d_in[14];
    const float* kg_W     = (const float*)d_in[15];
    const float* kg_b     = (const float*)d_in[16];
    const float* kg_lng   = (const float*)d_in[17];
    const float* kg_lnb   = (const float*)d_in[18];
    const float* type_emb = (const float*)d_in[19];
    const float* gat_W    = (const float*)d_in[20];
    const float* gat_b    = (const float*)d_in[21];
    const float* a_src    = (const float*)d_in[22];
    const float* a_dst    = (const float*)d_in[23];
    const float* gat_lng  = (const float*)d_in[24];
    const float* gat_lnb  = (const float*)d_in[25];
    const float* read_W   = (const float*)d_in[26];
    const float* read_b   = (const float*)d_in[27];
    const float* cs_W1    = (const float*)d_in[28];
    const float* cs_b1    = (const float*)d_in[29];
    const float* cs_W2    = (const float*)d_in[30];
    const float* cs_b2    = (const float*)d_in[31];
    float* out = (float*)d_out;

    float* ws = (float*)d_ws;
    const size_t NROW = (size_t)NB * NT;
    float* x      = ws;
    float* hbuf   = x + NROW * DH;
    float* obuf   = hbuf + NROW * DH;
    float* sbuf   = obuf + NROW * DH;
    float* tbuf   = sbuf + NB * NH * NT;
    float* mbuf   = tbuf + NB * NH * NT;
    float* lbuf   = mbuf + NB * NH * NT;
    float* pooled = lbuf + NB * NH * NT;
    float* scores = pooled + NB * DH;
    float* gpart  = scores + NROW;

    // 1. visual projection + LN -> x[:, 0:100]
    gemm_bias<<<dim3(8, (NB * NV + 127) / 128), 256, 0, stream>>>(
        visual, vis_W, vis_b, obuf, NB * NV, DH, DV);
    ln_scatter<<<NB * NV, 256, 0, stream>>>(obuf, x, vis_lng, vis_lnb, NB * NV, NV, 0);

    // 2. text pool + proj + LN -> x[:, 100]
    pool_kernel<<<NB, 256, 0, stream>>>(tok_emb, q_ids, q_mask, pooled);
    gemm_bias<<<dim3(8, 1), 256, 0, stream>>>(pooled, q_W, q_b, obuf, NB, DH, DH);
    ln_scatter<<<NB, 256, 0, stream>>>(obuf, x, q_lng, q_lnb, NB, 1, NV);

    // 3. KG projection + LN -> x[:, 101:1024]
    gemm_bias<<<dim3(8, (NB * NKG + 127) / 128), 256, 0, stream>>>(
        kg_feat, kg_W, kg_b, obuf, NB * NKG, DH, DK);
    ln_scatter<<<NB * NKG, 256, 0, stream>>>(obuf, x, kg_lng, kg_lnb, NB * NKG, NKG, NV + 1);

    // 4. + type embeddings
    type_add<<<NB * NT, 256, 0, stream>>>(x, ntypes, type_emb);

    // 5. GAT layers
    for (int l = 0; l < NLAYERS; ++l) {
        const float* Wl  = gat_W + (size_t)l * DH * DH;
        const float* bl  = gat_b + (size_t)l * DH;
        const float* asl = a_src + (size_t)l * NH * DHD;
        const float* adl = a_dst + (size_t)l * NH * DHD;
        gemm_bias<<<dim3(8, 64), 256, 0, stream>>>(x, Wl, bl, hbuf, NB * NT, DH, DH);
        st_kernel<<<NB * NT, 64, 0, stream>>>(hbuf, asl, adl, sbuf, tbuf);
        stats_kernel<<<NB * NT, 256, 0, stream>>>(adj, sbuf, tbuf, mbuf, lbuf);
        agg_kernel<<<dim3(16, NH, NB), 256, 0, stream>>>(hbuf, adj, sbuf, tbuf, mbuf, lbuf, obuf);
        ln_residual<<<NB * NT, 256, 0, stream>>>(x, obuf,
            gat_lng + (size_t)l * DH, gat_lnb + (size_t)l * DH);
    }

    // 6. readout + scorer
    score_kernel<<<NB * NT, 64, 0, stream>>>(x, read_W, read_b, scores);
    softmax_w<<<NB, 256, 0, stream>>>(scores);
    pool_part<<<dim3(8, NB), 256, 0, stream>>>(x, scores, gpart);
    scorer_kernel<<<NB, 256, 0, stream>>>(gpart, cs_W1, cs_b1, cs_W2, cs_b2, out);
}

// Round 3
// 1997.095 us; speedup vs baseline: 1.6496x; 1.4379x over previous
//
#include <hip/hip_runtime.h>
#include <math.h>

#define NB 8
#define NV 100
#define LQ 128
#define NKG 923
#define NT 1024
#define DV 2048
#define DK 300
#define DH 1024
#define NH 8
#define DHD 128
#define NLAYERS 3

typedef __attribute__((ext_vector_type(8))) short short8;
typedef __attribute__((ext_vector_type(4))) float f32x4;

__device__ __forceinline__ short f2bf(float f) {
    unsigned u = __float_as_uint(f);
    u += 0x7fff + ((u >> 16) & 1);   // round-to-nearest-even
    return (short)(u >> 16);
}

// ---------------- block reduce helpers (blockDim.x == 256) ----------------
__device__ __forceinline__ float block_reduce_sum(float v, float* red) {
    int tid = threadIdx.x;
    red[tid] = v; __syncthreads();
    for (int s = 128; s > 0; s >>= 1) {
        if (tid < s) red[tid] += red[tid + s];
        __syncthreads();
    }
    float r = red[0]; __syncthreads();
    return r;
}
__device__ __forceinline__ float block_reduce_max(float v, float* red) {
    int tid = threadIdx.x;
    red[tid] = v; __syncthreads();
    for (int s = 128; s > 0; s >>= 1) {
        if (tid < s) red[tid] = fmaxf(red[tid], red[tid + s]);
        __syncthreads();
    }
    float r = red[0]; __syncthreads();
    return r;
}

// ---------------- weight transpose-cast: out[N,Kp] bf16 <- in[K,N] fp32 ----
// zero-pads k in [K,Kp). grid (N/64, Kp/64), 256 threads.
__global__ __launch_bounds__(256) void transpose_cast(
    const float* __restrict__ in, short* __restrict__ out,
    int K, int N, int Kp)
{
    __shared__ float ls[64][65];
    int n0 = blockIdx.x * 64, k0 = blockIdx.y * 64;
    int tid = threadIdx.x;
    int j4 = (tid & 15) * 4;
#pragma unroll
    for (int s = 0; s < 4; ++s) {
        int i = (tid >> 4) + s * 16;      // k offset in tile
        int k = k0 + i;
        float4 v = make_float4(0.f, 0.f, 0.f, 0.f);
        if (k < K) v = *(const float4*)(in + (size_t)k * N + n0 + j4);
        ls[i][j4 + 0] = v.x; ls[i][j4 + 1] = v.y;
        ls[i][j4 + 2] = v.z; ls[i][j4 + 3] = v.w;
    }
    __syncthreads();
#pragma unroll
    for (int s = 0; s < 4; ++s) {
        int a = (tid >> 4) + s * 16;      // n offset in tile
        int b = (tid & 15) * 4;           // k offset in tile
        unsigned short t0 = (unsigned short)f2bf(ls[b + 0][a]);
        unsigned short t1 = (unsigned short)f2bf(ls[b + 1][a]);
        unsigned short t2 = (unsigned short)f2bf(ls[b + 2][a]);
        unsigned short t3 = (unsigned short)f2bf(ls[b + 3][a]);
        uint2 pk;
        pk.x = (unsigned)t0 | ((unsigned)t1 << 16);
        pk.y = (unsigned)t2 | ((unsigned)t3 << 16);
        *(uint2*)(out + (size_t)(n0 + a) * Kp + k0 + b) = pk;
    }
}

// ---------------- MFMA GEMM: C[M,N] = A[M,K](fp32) @ Wt[N,Kp](bf16)^T + bias -
// 128x128 tile, BK=32, 256 threads (4 waves, each 64x64 via 4x4 MFMA 16x16x32).
// A cast to bf16 inline during staging; Wt is pre-transposed bf16 (k zero-padded).
__global__ __launch_bounds__(256) void gemm_bias_mfma(
    const float* __restrict__ A, const short* __restrict__ Wt,
    const float* __restrict__ bias, float* __restrict__ C,
    int M, int N, int K, int Kp, int ldA)
{
    __shared__ short At[128][32];   // [m][k] bf16
    __shared__ short Bt[128][32];   // [n][k] bf16
    int tid = threadIdx.x;
    int row0 = blockIdx.y * 128, col0 = blockIdx.x * 128;
    int lane = tid & 63, wave = tid >> 6;
    int quad = lane >> 4, lq = lane & 15;
    int wm = (wave >> 1) * 64, wn = (wave & 1) * 64;
    f32x4 acc[4][4];
#pragma unroll
    for (int i = 0; i < 4; ++i)
#pragma unroll
        for (int j = 0; j < 4; ++j) {
            f32x4 z = {0.f, 0.f, 0.f, 0.f};
            acc[i][j] = z;
        }

    int ar = tid >> 2;            // 0..63 (row within half-tile)
    int ac = (tid & 3) * 8;       // k chunk 0,8,16,24
    for (int k0 = 0; k0 < Kp; k0 += 32) {
        bool fullk = (k0 + 32 <= K);
        // stage A (fp32 -> bf16), conflict-free contiguous b128 writes
#pragma unroll
        for (int s = 0; s < 2; ++s) {
            int r = ar + s * 64;
            int grow = row0 + r;
            short8 pk;
            if (grow < M && fullk) {
                const float* src = A + (size_t)grow * ldA + k0 + ac;
                float4 v0 = *(const float4*)(src);
                float4 v1 = *(const float4*)(src + 4);
                pk[0] = f2bf(v0.x); pk[1] = f2bf(v0.y);
                pk[2] = f2bf(v0.z); pk[3] = f2bf(v0.w);
                pk[4] = f2bf(v1.x); pk[5] = f2bf(v1.y);
                pk[6] = f2bf(v1.z); pk[7] = f2bf(v1.w);
            } else {
#pragma unroll
                for (int e = 0; e < 8; ++e) {
                    int k = k0 + ac + e;
                    pk[e] = (grow < M && k < K)
                          ? f2bf(A[(size_t)grow * ldA + k]) : (short)0;
                }
            }
            *(short8*)&At[r][ac] = pk;
        }
        // stage Wt rows (already bf16, already zero-padded)
#pragma unroll
        for (int s = 0; s < 2; ++s) {
            int n = ar + s * 64;
            short8 w = *(const short8*)(Wt + (size_t)(col0 + n) * Kp + k0 + ac);
            *(short8*)&Bt[n][ac] = w;
        }
        __syncthreads();
        short8 af[4], bfr[4];
#pragma unroll
        for (int i = 0; i < 4; ++i)
            af[i] = *(short8*)&At[wm + i * 16 + lq][quad * 8];
#pragma unroll
        for (int j = 0; j < 4; ++j)
            bfr[j] = *(short8*)&Bt[wn + j * 16 + lq][quad * 8];
#pragma unroll
        for (int i = 0; i < 4; ++i)
#pragma unroll
            for (int j = 0; j < 4; ++j)
                acc[i][j] = __builtin_amdgcn_mfma_f32_16x16x32_bf16(
                    af[i], bfr[j], acc[i][j], 0, 0, 0);
        __syncthreads();
    }
    // epilogue: C/D layout col=lane&15 (n), row=quad*4+reg (m)
#pragma unroll
    for (int j = 0; j < 4; ++j) {
        int n = col0 + wn + j * 16 + lq;
        float bv = bias[n];
#pragma unroll
        for (int i = 0; i < 4; ++i) {
#pragma unroll
            for (int r = 0; r < 4; ++r) {
                int m = row0 + wm + i * 16 + quad * 4 + r;
                if (m < M) C[(size_t)m * N + n] = acc[i][j][r] + bv;
            }
        }
    }
}

// ---------------- LayerNorm + scatter into x ----------------
__global__ __launch_bounds__(256) void ln_scatter(
    const float* __restrict__ src, float* __restrict__ x,
    const float* __restrict__ g, const float* __restrict__ bta,
    int rows, int npb, int node_off)
{
    __shared__ float red[256];
    int r = blockIdx.x;
    if (r >= rows) return;
    int tid = threadIdx.x;
    int b = r / npb, n = r % npb;
    float4 v = *(const float4*)(src + (size_t)r * DH + tid * 4);
    float s = v.x + v.y + v.z + v.w;
    float sq = v.x * v.x + v.y * v.y + v.z * v.z + v.w * v.w;
    float tot = block_reduce_sum(s, red);
    float totsq = block_reduce_sum(sq, red);
    float mean = tot * (1.0f / DH);
    float var = totsq * (1.0f / DH) - mean * mean;
    float rstd = 1.0f / sqrtf(var + 1e-5f);
    float4 gv = *(const float4*)(g + tid * 4);
    float4 bv = *(const float4*)(bta + tid * 4);
    float4 o;
    o.x = (v.x - mean) * rstd * gv.x + bv.x;
    o.y = (v.y - mean) * rstd * gv.y + bv.y;
    o.z = (v.z - mean) * rstd * gv.z + bv.z;
    o.w = (v.w - mean) * rstd * gv.w + bv.w;
    *(float4*)(x + ((size_t)(b * NT + node_off + n)) * DH + tid * 4) = o;
}

// ---------------- residual + LayerNorm in-place on x ----------------
__global__ __launch_bounds__(256) void ln_residual(
    float* __restrict__ x, const float* __restrict__ o,
    const float* __restrict__ g, const float* __restrict__ bta)
{
    __shared__ float red[256];
    int r = blockIdx.x;
    int tid = threadIdx.x;
    float* xr = x + (size_t)r * DH;
    float4 xv = *(float4*)(xr + tid * 4);
    float4 ov = *(const float4*)(o + (size_t)r * DH + tid * 4);
    float v0 = xv.x + ov.x, v1 = xv.y + ov.y, v2 = xv.z + ov.z, v3 = xv.w + ov.w;
    float s = v0 + v1 + v2 + v3;
    float sq = v0 * v0 + v1 * v1 + v2 * v2 + v3 * v3;
    float tot = block_reduce_sum(s, red);
    float totsq = block_reduce_sum(sq, red);
    float mean = tot * (1.0f / DH);
    float var = totsq * (1.0f / DH) - mean * mean;
    float rstd = 1.0f / sqrtf(var + 1e-5f);
    float4 gv = *(const float4*)(g + tid * 4);
    float4 bv = *(const float4*)(bta + tid * 4);
    float4 out;
    out.x = (v0 - mean) * rstd * gv.x + bv.x;
    out.y = (v1 - mean) * rstd * gv.y + bv.y;
    out.z = (v2 - mean) * rstd * gv.z + bv.z;
    out.w = (v3 - mean) * rstd * gv.w + bv.w;
    *(float4*)(xr + tid * 4) = out;
}

// ---------------- text: masked mean pool of token embeddings ----------------
__global__ __launch_bounds__(256) void pool_kernel(
    const float* __restrict__ tok_emb, const int* __restrict__ ids,
    const int* __restrict__ amask, float* __restrict__ pooled)
{
    int b = blockIdx.x;
    int tid = threadIdx.x;
    float a0 = 0, a1 = 0, a2 = 0, a3 = 0;
    float denom = 0;
    for (int l = 0; l < LQ; ++l) {
        int id = ids[b * LQ + l];
        float m = (float)amask[b * LQ + l];
        denom += m;
        float4 e = *(const float4*)(tok_emb + (size_t)id * DH + tid * 4);
        a0 += m * e.x; a1 += m * e.y; a2 += m * e.z; a3 += m * e.w;
    }
    float inv = 1.0f / fmaxf(denom, 1.0f);
    float4 o = make_float4(a0 * inv, a1 * inv, a2 * inv, a3 * inv);
    *(float4*)(pooled + b * DH + tid * 4) = o;
}

// ---------------- add type embeddings ----------------
__global__ __launch_bounds__(256) void type_add(
    float* __restrict__ x, const int* __restrict__ types,
    const float* __restrict__ type_emb)
{
    int r = blockIdx.x;
    int tid = threadIdx.x;
    int ty = types[r];
    float4 xv = *(float4*)(x + (size_t)r * DH + tid * 4);
    float4 tv = *(const float4*)(type_emb + (size_t)ty * DH + tid * 4);
    xv.x += tv.x; xv.y += tv.y; xv.z += tv.z; xv.w += tv.w;
    *(float4*)(x + (size_t)r * DH + tid * 4) = xv;
}

// ---------------- GAT: s/t head scores, one wave per node row ----------------
__global__ __launch_bounds__(64) void st_kernel(
    const float* __restrict__ hbuf, const float* __restrict__ asrc,
    const float* __restrict__ adst, float* __restrict__ s, float* __restrict__ t)
{
    int r = blockIdx.x;
    int lane = threadIdx.x;
    int b = r >> 10, n = r & 1023;
    const float* hrow = hbuf + (size_t)r * DH;
    for (int h = 0; h < NH; ++h) {
        float2 v = *(const float2*)(hrow + h * DHD + lane * 2);
        float2 s2 = *(const float2*)(asrc + h * DHD + lane * 2);
        float2 t2 = *(const float2*)(adst + h * DHD + lane * 2);
        float ps = v.x * s2.x + v.y * s2.y;
        float pt = v.x * t2.x + v.y * t2.y;
        for (int off = 32; off > 0; off >>= 1) {
            ps += __shfl_down(ps, off, 64);
            pt += __shfl_down(pt, off, 64);
        }
        if (lane == 0) {
            s[(size_t)(b * NH + h) * NT + n] = ps;
            t[(size_t)(b * NH + h) * NT + n] = pt;
        }
    }
}

// ---------------- GAT: masked softmax row stats (max m, inv sum) ----------------
__global__ __launch_bounds__(256) void stats_kernel(
    const int* __restrict__ adj, const float* __restrict__ s,
    const float* __restrict__ t, float* __restrict__ mbuf, float* __restrict__ lbuf)
{
    __shared__ float red[256];
    __shared__ unsigned char mrow[NT];
    int bi = blockIdx.x;
    int b = bi >> 10, i = bi & 1023;
    int tid = threadIdx.x;
    const int* arow = adj + (size_t)bi * NT;
    for (int j = tid; j < NT; j += 256) mrow[j] = (unsigned char)(arow[j] > 0);
    __syncthreads();
    for (int h = 0; h < NH; ++h) {
        const float* tp = t + (size_t)(b * NH + h) * NT;
        float si = s[(size_t)(b * NH + h) * NT + i];
        float vals[4];
        float mx = -3e38f;
#pragma unroll
        for (int k = 0; k < 4; ++k) {
            int j = tid + k * 256;
            float v = si + tp[j];
            v = v > 0.f ? v : 0.2f * v;
            v = mrow[j] ? v : -1e9f;
            vals[k] = v;
            mx = fmaxf(mx, v);
        }
        float m = block_reduce_max(mx, red);
        float ls = 0.f;
#pragma unroll
        for (int k = 0; k < 4; ++k) ls += __expf(vals[k] - m);
        float tot = block_reduce_sum(ls, red);
        if (tid == 0) {
            mbuf[(size_t)(b * NH + h) * NT + i] = m;
            lbuf[(size_t)(b * NH + h) * NT + i] = 1.0f / tot;
        }
        __syncthreads();
    }
}

// ---------------- GAT: attention aggregation ----------------
__global__ __launch_bounds__(256) void agg_kernel(
    const float* __restrict__ hbuf, const int* __restrict__ adj,
    const float* __restrict__ s, const float* __restrict__ t,
    const float* __restrict__ mbuf, const float* __restrict__ lbuf,
    float* __restrict__ obuf)
{
    __shared__ float vt[64][128];
    __shared__ float at[64][68];
    __shared__ float sv[64], mv[64], lv[64], tv[64];
    int i0 = blockIdx.x * 64;
    int h = blockIdx.y;
    int b = blockIdx.z;
    int tid = threadIdx.x;
    int tx = tid & 15;
    int ty = tid >> 4;
    if (tid < 64) {
        size_t idx = (size_t)(b * NH + h) * NT + i0 + tid;
        sv[tid] = s[idx]; mv[tid] = mbuf[idx]; lv[tid] = lbuf[idx];
    }
    float acc[4][8] = {};
    const float* tptr = t + (size_t)(b * NH + h) * NT;
    for (int j0 = 0; j0 < NT; j0 += 64) {
        __syncthreads();
        if (tid < 64) tv[tid] = tptr[j0 + tid];
#pragma unroll
        for (int it = 0; it < 8; ++it) {
            int f = tid + it * 256;
            int jj = f >> 5, d4 = (f & 31) * 4;
            *(float4*)&vt[jj][d4] =
                *(const float4*)(hbuf + ((size_t)(b * NT + j0 + jj)) * DH + h * DHD + d4);
        }
        __syncthreads();
#pragma unroll
        for (int k = 0; k < 4; ++k) {
            int f = tid + k * 256;
            int ii = f >> 4, jq = (f & 15) * 4;
            int4 a4 = *(const int4*)(adj + ((size_t)(b * NT + i0 + ii)) * NT + j0 + jq);
            float svv = sv[ii], mvv = mv[ii], lvv = lv[ii];
            float4 o; float v;
            v = svv + tv[jq + 0]; v = v > 0.f ? v : 0.2f * v; o.x = a4.x > 0 ? __expf(v - mvv) * lvv : 0.f;
            v = svv + tv[jq + 1]; v = v > 0.f ? v : 0.2f * v; o.y = a4.y > 0 ? __expf(v - mvv) * lvv : 0.f;
            v = svv + tv[jq + 2]; v = v > 0.f ? v : 0.2f * v; o.z = a4.z > 0 ? __expf(v - mvv) * lvv : 0.f;
            v = svv + tv[jq + 3]; v = v > 0.f ? v : 0.2f * v; o.w = a4.w > 0 ? __expf(v - mvv) * lvv : 0.f;
            *(float4*)&at[ii][jq] = o;
        }
        __syncthreads();
#pragma unroll 4
        for (int jj = 0; jj < 64; jj += 4) {
            float4 av0 = *(float4*)&at[ty * 4 + 0][jj];
            float4 av1 = *(float4*)&at[ty * 4 + 1][jj];
            float4 av2 = *(float4*)&at[ty * 4 + 2][jj];
            float4 av3 = *(float4*)&at[ty * 4 + 3][jj];
            float aq[4][4] = {{av0.x, av0.y, av0.z, av0.w},
                              {av1.x, av1.y, av1.z, av1.w},
                              {av2.x, av2.y, av2.z, av2.w},
                              {av3.x, av3.y, av3.z, av3.w}};
#pragma unroll
            for (int p = 0; p < 4; ++p) {
                float4 v0 = *(float4*)&vt[jj + p][tx * 8];
                float4 v1 = *(float4*)&vt[jj + p][tx * 8 + 4];
                float vd[8] = {v0.x, v0.y, v0.z, v0.w, v1.x, v1.y, v1.z, v1.w};
#pragma unroll
                for (int q = 0; q < 4; ++q) {
                    float a = aq[q][p];
#pragma unroll
                    for (int d = 0; d < 8; ++d) acc[q][d] += a * vd[d];
                }
            }
        }
    }
#pragma unroll
    for (int q = 0; q < 4; ++q) {
        int i = i0 + ty * 4 + q;
        float4 o0 = make_float4(acc[q][0], acc[q][1], acc[q][2], acc[q][3]);
        float4 o1 = make_float4(acc[q][4], acc[q][5], acc[q][6], acc[q][7]);
        float* dst = obuf + ((size_t)(b * NT + i)) * DH + h * DHD + tx * 8;
        *(float4*)dst = o0;
        *(float4*)(dst + 4) = o1;
    }
}

// ---------------- readout scores: one wave per node ----------------
__global__ __launch_bounds__(64) void score_kernel(
    const float* __restrict__ x, const float* __restrict__ rW,
    const float* __restrict__ rb, float* __restrict__ scores)
{
    int r = blockIdx.x;
    int lane = threadIdx.x;
    const float* xr = x + (size_t)r * DH;
    float acc = 0.f;
#pragma unroll
    for (int k = 0; k < 4; ++k) {
        float4 xv = *(const float4*)(xr + lane * 16 + k * 4);
        float4 wv = *(const float4*)(rW + lane * 16 + k * 4);
        acc += xv.x * wv.x + xv.y * wv.y + xv.z * wv.z + xv.w * wv.w;
    }
    for (int off = 32; off > 0; off >>= 1) acc += __shfl_down(acc, off, 64);
    if (lane == 0) scores[r] = acc + rb[0];
}

// ---------------- per-batch softmax over node scores (in place) ----------------
__global__ __launch_bounds__(256) void softmax_w(float* __restrict__ scores)
{
    __shared__ float red[256];
    int b = blockIdx.x;
    int tid = threadIdx.x;
    float* sr = scores + (size_t)b * NT;
    float v[4];
    float mx = -3e38f;
#pragma unroll
    for (int k = 0; k < 4; ++k) { v[k] = sr[tid + k * 256]; mx = fmaxf(mx, v[k]); }
    float m = block_reduce_max(mx, red);
    float ls = 0.f;
#pragma unroll
    for (int k = 0; k < 4; ++k) { v[k] = expf(v[k] - m); ls += v[k]; }
    float tot = block_reduce_sum(ls, red);
    float inv = 1.0f / tot;
#pragma unroll
    for (int k = 0; k < 4; ++k) sr[tid + k * 256] = v[k] * inv;
}

// ---------------- weighted pool partials ----------------
__global__ __launch_bounds__(256) void pool_part(
    const float* __restrict__ x, const float* __restrict__ w,
    float* __restrict__ gpart)
{
    int p = blockIdx.x;
    int b = blockIdx.y;
    int tid = threadIdx.x;
    float a0 = 0, a1 = 0, a2 = 0, a3 = 0;
    for (int n = p * 128; n < (p + 1) * 128; ++n) {
        float wv = w[(size_t)b * NT + n];
        float4 xv = *(const float4*)(x + ((size_t)(b * NT + n)) * DH + tid * 4);
        a0 += wv * xv.x; a1 += wv * xv.y; a2 += wv * xv.z; a3 += wv * xv.w;
    }
    float4 o = make_float4(a0, a1, a2, a3);
    *(float4*)(gpart + ((size_t)(b * 8 + p)) * DH + tid * 4) = o;
}

// ---------------- final candidate scorer ----------------
__global__ __launch_bounds__(256) void scorer_kernel(
    const float* __restrict__ gpart, const float* __restrict__ W1,
    const float* __restrict__ b1, const float* __restrict__ W2,
    const float* __restrict__ b2, float* __restrict__ out)
{
    __shared__ float gsh[DH];
    __shared__ float red[256];
    int b = blockIdx.x;
    int tid = threadIdx.x;
#pragma unroll
    for (int c = 0; c < 4; ++c) {
        int d = tid + c * 256;
        float gv = 0.f;
        for (int p = 0; p < 8; ++p) gv += gpart[((size_t)(b * 8 + p)) * DH + d];
        gsh[d] = gv;
    }
    __syncthreads();
    float acc[4] = {};
    for (int d = 0; d < DH; ++d) {
        float gv = gsh[d];
        const float* wr = W1 + (size_t)d * DH;
#pragma unroll
        for (int c = 0; c < 4; ++c) acc[c] += gv * wr[tid + c * 256];
    }
    float part = 0.f;
#pragma unroll
    for (int c = 0; c < 4; ++c) {
        int k = tid + c * 256;
        float u = acc[c] + b1[k];
        float inner = 0.7978845608028654f * (u + 0.044715f * u * u * u);
        float gel = 0.5f * u * (1.0f + tanhf(inner));
        part += gel * W2[k];
    }
    float tot = block_reduce_sum(part, red);
    if (tid == 0) out[b] = tot + b2[0];
}

// ---------------- launch ----------------
extern "C" void kernel_launch(void* const* d_in, const int* in_sizes, int n_in,
                              void* d_out, int out_size, void* d_ws, size_t ws_size,
                              hipStream_t stream)
{
    const float* visual   = (const float*)d_in[0];
    const int*   q_ids    = (const int*)d_in[1];
    const int*   q_mask   = (const int*)d_in[2];
    const float* kg_feat  = (const float*)d_in[3];
    const int*   adj      = (const int*)d_in[4];
    const int*   ntypes   = (const int*)d_in[5];
    const float* vis_W    = (const float*)d_in[6];
    const float* vis_b    = (const float*)d_in[7];
    const float* vis_lng  = (const float*)d_in[8];
    const float* vis_lnb  = (const float*)d_in[9];
    const float* tok_emb  = (const float*)d_in[10];
    const float* q_W      = (const float*)d_in[11];
    const float* q_b      = (const float*)d_in[12];
    const float* q_lng    = (const float*)d_in[13];
    const float* q_lnb    = (const float*)d_in[14];
    const float* kg_W     = (const float*)d_in[15];
    const float* kg_b     = (const float*)d_in[16];
    const float* kg_lng   = (const float*)d_in[17];
    const float* kg_lnb   = (const float*)d_in[18];
    const float* type_emb = (const float*)d_in[19];
    const float* gat_W    = (const float*)d_in[20];
    const float* gat_b    = (const float*)d_in[21];
    const float* a_src    = (const float*)d_in[22];
    const float* a_dst    = (const float*)d_in[23];
    const float* gat_lng  = (const float*)d_in[24];
    const float* gat_lnb  = (const float*)d_in[25];
    const float* read_W   = (const float*)d_in[26];
    const float* read_b   = (const float*)d_in[27];
    const float* cs_W1    = (const float*)d_in[28];
    const float* cs_b1    = (const float*)d_in[29];
    const float* cs_W2    = (const float*)d_in[30];
    const float* cs_b2    = (const float*)d_in[31];
    float* out = (float*)d_out;

    float* ws = (float*)d_ws;
    const size_t NROW = (size_t)NB * NT;
    float* x      = ws;                       // 8M floats
    float* hbuf   = x + NROW * DH;            // 8M floats
    float* obuf   = hbuf + NROW * DH;         // 8M floats
    float* sbuf   = obuf + NROW * DH;
    float* tbuf   = sbuf + NB * NH * NT;
    float* mbuf   = tbuf + NB * NH * NT;
    float* lbuf   = mbuf + NB * NH * NT;
    float* pooled = lbuf + NB * NH * NT;
    float* scores = pooled + NB * DH;
    float* gpart  = scores + NROW;
    short* wt_gat = (short*)(gpart + NB * 8 * DH);          // 3 x 1M shorts
    // projection weights (dead before first hbuf write) alias into hbuf
    short* wt_vis = (short*)hbuf;                           // 1024x2048
    short* wt_q   = wt_vis + (size_t)1024 * 2048;           // 1024x1024
    short* wt_kg  = wt_q + (size_t)1024 * 1024;             // 1024x320

    // 0. transpose-cast all weights to bf16 [N, Kp]
    transpose_cast<<<dim3(16, 32), 256, 0, stream>>>(vis_W, wt_vis, DV, DH, DV);
    transpose_cast<<<dim3(16, 16), 256, 0, stream>>>(q_W, wt_q, DH, DH, DH);
    transpose_cast<<<dim3(16, 5), 256, 0, stream>>>(kg_W, wt_kg, DK, DH, 320);
    for (int l = 0; l < NLAYERS; ++l)
        transpose_cast<<<dim3(16, 16), 256, 0, stream>>>(
            gat_W + (size_t)l * DH * DH, wt_gat + (size_t)l * DH * DH, DH, DH, DH);

    // 1. visual projection + LN -> x[:, 0:100]
    gemm_bias_mfma<<<dim3(8, 7), 256, 0, stream>>>(
        visual, wt_vis, vis_b, obuf, NB * NV, DH, DV, DV, DV);
    ln_scatter<<<NB * NV, 256, 0, stream>>>(obuf, x, vis_lng, vis_lnb, NB * NV, NV, 0);

    // 2. text pool + proj + LN -> x[:, 100]
    pool_kernel<<<NB, 256, 0, stream>>>(tok_emb, q_ids, q_mask, pooled);
    gemm_bias_mfma<<<dim3(8, 1), 256, 0, stream>>>(
        pooled, wt_q, q_b, obuf, NB, DH, DH, DH, DH);
    ln_scatter<<<NB, 256, 0, stream>>>(obuf, x, q_lng, q_lnb, NB, 1, NV);

    // 3. KG projection + LN -> x[:, 101:1024]
    gemm_bias_mfma<<<dim3(8, 58), 256, 0, stream>>>(
        kg_feat, wt_kg, kg_b, obuf, NB * NKG, DH, DK, 320, DK);
    ln_scatter<<<NB * NKG, 256, 0, stream>>>(obuf, x, kg_lng, kg_lnb, NB * NKG, NKG, NV + 1);

    // 4. + type embeddings
    type_add<<<NB * NT, 256, 0, stream>>>(x, ntypes, type_emb);

    // 5. GAT layers
    for (int l = 0; l < NLAYERS; ++l) {
        const float* bl  = gat_b + (size_t)l * DH;
        const float* asl = a_src + (size_t)l * NH * DHD;
        const float* adl = a_dst + (size_t)l * NH * DHD;
        gemm_bias_mfma<<<dim3(8, 64), 256, 0, stream>>>(
            x, wt_gat + (size_t)l * DH * DH, bl, hbuf, NB * NT, DH, DH, DH, DH);
        st_kernel<<<NB * NT, 64, 0, stream>>>(hbuf, asl, adl, sbuf, tbuf);
        stats_kernel<<<NB * NT, 256, 0, stream>>>(adj, sbuf, tbuf, mbuf, lbuf);
        agg_kernel<<<dim3(16, NH, NB), 256, 0, stream>>>(hbuf, adj, sbuf, tbuf, mbuf, lbuf, obuf);
        ln_residual<<<NB * NT, 256, 0, stream>>>(x, obuf,
            gat_lng + (size_t)l * DH, gat_lnb + (size_t)l * DH);
    }

    // 6. readout + scorer
    score_kernel<<<NB * NT, 64, 0, stream>>>(x, read_W, read_b, scores);
    softmax_w<<<NB, 256, 0, stream>>>(scores);
    pool_part<<<dim3(8, NB), 256, 0, stream>>>(x, scores, gpart);
    scorer_kernel<<<NB, 256, 0, stream>>>(gpart, cs_W1, cs_b1, cs_W2, cs_b2, out);
}

// Round 4
// 1360.202 us; speedup vs baseline: 2.4220x; 1.4682x over previous
//
#include <hip/hip_runtime.h>
#include <math.h>

#define NB 8
#define NV 100
#define LQ 128
#define NKG 923
#define NT 1024
#define DV 2048
#define DK 300
#define DH 1024
#define NH 8
#define DHD 128
#define NLAYERS 3

typedef __attribute__((ext_vector_type(8))) short short8;
typedef __attribute__((ext_vector_type(4))) float f32x4;

__device__ __forceinline__ short f2bf(float f) {
    unsigned u = __float_as_uint(f);
    u += 0x7fff + ((u >> 16) & 1);   // round-to-nearest-even
    return (short)(u >> 16);
}

// ---------------- block reduce helpers (blockDim.x == 256) ----------------
__device__ __forceinline__ float block_reduce_sum(float v, float* red) {
    int tid = threadIdx.x;
    red[tid] = v; __syncthreads();
    for (int s = 128; s > 0; s >>= 1) {
        if (tid < s) red[tid] += red[tid + s];
        __syncthreads();
    }
    float r = red[0]; __syncthreads();
    return r;
}
__device__ __forceinline__ float block_reduce_max(float v, float* red) {
    int tid = threadIdx.x;
    red[tid] = v; __syncthreads();
    for (int s = 128; s > 0; s >>= 1) {
        if (tid < s) red[tid] = fmaxf(red[tid], red[tid + s]);
        __syncthreads();
    }
    float r = red[0]; __syncthreads();
    return r;
}

// ---------------- adjacency -> bitmask: mb[b*NT+i][w] (32 u32 per row) -----
__global__ __launch_bounds__(256) void bitmask_kernel(
    const int* __restrict__ adj, unsigned* __restrict__ mb)
{
    int bi = blockIdx.x;            // b*NT + i
    int tid = threadIdx.x;
#pragma unroll
    for (int p = 0; p < 4; ++p) {
        int j = p * 256 + tid;
        unsigned long long bal = __ballot(adj[(size_t)bi * NT + j] > 0);
        if ((tid & 63) == 0) {
            int w = (p * 256 + (tid & 0xC0)) >> 5;
            mb[(size_t)bi * 32 + w]     = (unsigned)bal;
            mb[(size_t)bi * 32 + w + 1] = (unsigned)(bal >> 32);
        }
    }
}

// ---------------- weight transpose-cast: out[N,Kp] bf16 <- in[K,N] fp32 ----
__global__ __launch_bounds__(256) void transpose_cast(
    const float* __restrict__ in, short* __restrict__ out,
    int K, int N, int Kp)
{
    __shared__ float ls[64][65];
    int n0 = blockIdx.x * 64, k0 = blockIdx.y * 64;
    int tid = threadIdx.x;
    int j4 = (tid & 15) * 4;
#pragma unroll
    for (int s = 0; s < 4; ++s) {
        int i = (tid >> 4) + s * 16;
        int k = k0 + i;
        float4 v = make_float4(0.f, 0.f, 0.f, 0.f);
        if (k < K) v = *(const float4*)(in + (size_t)k * N + n0 + j4);
        ls[i][j4 + 0] = v.x; ls[i][j4 + 1] = v.y;
        ls[i][j4 + 2] = v.z; ls[i][j4 + 3] = v.w;
    }
    __syncthreads();
#pragma unroll
    for (int s = 0; s < 4; ++s) {
        int a = (tid >> 4) + s * 16;
        int b = (tid & 15) * 4;
        unsigned short t0 = (unsigned short)f2bf(ls[b + 0][a]);
        unsigned short t1 = (unsigned short)f2bf(ls[b + 1][a]);
        unsigned short t2 = (unsigned short)f2bf(ls[b + 2][a]);
        unsigned short t3 = (unsigned short)f2bf(ls[b + 3][a]);
        uint2 pk;
        pk.x = (unsigned)t0 | ((unsigned)t1 << 16);
        pk.y = (unsigned)t2 | ((unsigned)t3 << 16);
        *(uint2*)(out + (size_t)(n0 + a) * Kp + k0 + b) = pk;
    }
}

// ---------------- h transpose: ht[b,h,d][j] bf16 <- hbuf[b*NT+j][h*DHD+d] ---
// grid (NT/64, DHD/64, NB*NH)
__global__ __launch_bounds__(256) void transpose_h(
    const float* __restrict__ hbuf, short* __restrict__ ht)
{
    __shared__ float ls[64][65];
    int j0 = blockIdx.x * 64;
    int d0 = blockIdx.y * 64;
    int bh = blockIdx.z;            // b*NH + h
    int b = bh >> 3, h = bh & 7;
    int tid = threadIdx.x;
    int c4 = (tid & 15) * 4;
#pragma unroll
    for (int s = 0; s < 4; ++s) {
        int jj = (tid >> 4) + s * 16;
        float4 v = *(const float4*)(
            hbuf + ((size_t)(b * NT + j0 + jj)) * DH + h * DHD + d0 + c4);
        ls[jj][c4 + 0] = v.x; ls[jj][c4 + 1] = v.y;
        ls[jj][c4 + 2] = v.z; ls[jj][c4 + 3] = v.w;
    }
    __syncthreads();
    int od = tid >> 2;              // 0..63
    int jseg = (tid & 3) * 16;
    short8 s0, s1;
#pragma unroll
    for (int e = 0; e < 8; ++e) s0[e] = f2bf(ls[jseg + e][od]);
#pragma unroll
    for (int e = 0; e < 8; ++e) s1[e] = f2bf(ls[jseg + 8 + e][od]);
    short* dst = ht + ((size_t)bh * DHD + d0 + od) * NT + j0 + jseg;
    *(short8*)dst = s0;
    *(short8*)(dst + 8) = s1;
}

// ---------------- MFMA GEMM: C[M,N] = A[M,K](fp32) @ Wt[N,Kp](bf16)^T + bias -
__global__ __launch_bounds__(256) void gemm_bias_mfma(
    const float* __restrict__ A, const short* __restrict__ Wt,
    const float* __restrict__ bias, float* __restrict__ C,
    int M, int N, int K, int Kp, int ldA)
{
    __shared__ short At[128][32];
    __shared__ short Bt[128][32];
    int tid = threadIdx.x;
    int row0 = blockIdx.y * 128, col0 = blockIdx.x * 128;
    int lane = tid & 63, wave = tid >> 6;
    int quad = lane >> 4, lq = lane & 15;
    int wm = (wave >> 1) * 64, wn = (wave & 1) * 64;
    f32x4 acc[4][4];
#pragma unroll
    for (int i = 0; i < 4; ++i)
#pragma unroll
        for (int j = 0; j < 4; ++j) {
            f32x4 z = {0.f, 0.f, 0.f, 0.f};
            acc[i][j] = z;
        }

    int ar = tid >> 2;
    int ac = (tid & 3) * 8;
    for (int k0 = 0; k0 < Kp; k0 += 32) {
        bool fullk = (k0 + 32 <= K);
#pragma unroll
        for (int s = 0; s < 2; ++s) {
            int r = ar + s * 64;
            int grow = row0 + r;
            short8 pk;
            if (grow < M && fullk) {
                const float* src = A + (size_t)grow * ldA + k0 + ac;
                float4 v0 = *(const float4*)(src);
                float4 v1 = *(const float4*)(src + 4);
                pk[0] = f2bf(v0.x); pk[1] = f2bf(v0.y);
                pk[2] = f2bf(v0.z); pk[3] = f2bf(v0.w);
                pk[4] = f2bf(v1.x); pk[5] = f2bf(v1.y);
                pk[6] = f2bf(v1.z); pk[7] = f2bf(v1.w);
            } else {
#pragma unroll
                for (int e = 0; e < 8; ++e) {
                    int k = k0 + ac + e;
                    pk[e] = (grow < M && k < K)
                          ? f2bf(A[(size_t)grow * ldA + k]) : (short)0;
                }
            }
            *(short8*)&At[r][ac] = pk;
        }
#pragma unroll
        for (int s = 0; s < 2; ++s) {
            int n = ar + s * 64;
            short8 w = *(const short8*)(Wt + (size_t)(col0 + n) * Kp + k0 + ac);
            *(short8*)&Bt[n][ac] = w;
        }
        __syncthreads();
        short8 af[4], bfr[4];
#pragma unroll
        for (int i = 0; i < 4; ++i)
            af[i] = *(short8*)&At[wm + i * 16 + lq][quad * 8];
#pragma unroll
        for (int j = 0; j < 4; ++j)
            bfr[j] = *(short8*)&Bt[wn + j * 16 + lq][quad * 8];
#pragma unroll
        for (int i = 0; i < 4; ++i)
#pragma unroll
            for (int j = 0; j < 4; ++j)
                acc[i][j] = __builtin_amdgcn_mfma_f32_16x16x32_bf16(
                    af[i], bfr[j], acc[i][j], 0, 0, 0);
        __syncthreads();
    }
#pragma unroll
    for (int j = 0; j < 4; ++j) {
        int n = col0 + wn + j * 16 + lq;
        float bv = bias[n];
#pragma unroll
        for (int i = 0; i < 4; ++i) {
#pragma unroll
            for (int r = 0; r < 4; ++r) {
                int m = row0 + wm + i * 16 + quad * 4 + r;
                if (m < M) C[(size_t)m * N + n] = acc[i][j][r] + bv;
            }
        }
    }
}

// ---------------- LayerNorm + scatter into x ----------------
__global__ __launch_bounds__(256) void ln_scatter(
    const float* __restrict__ src, float* __restrict__ x,
    const float* __restrict__ g, const float* __restrict__ bta,
    int rows, int npb, int node_off)
{
    __shared__ float red[256];
    int r = blockIdx.x;
    if (r >= rows) return;
    int tid = threadIdx.x;
    int b = r / npb, n = r % npb;
    float4 v = *(const float4*)(src + (size_t)r * DH + tid * 4);
    float s = v.x + v.y + v.z + v.w;
    float sq = v.x * v.x + v.y * v.y + v.z * v.z + v.w * v.w;
    float tot = block_reduce_sum(s, red);
    float totsq = block_reduce_sum(sq, red);
    float mean = tot * (1.0f / DH);
    float var = totsq * (1.0f / DH) - mean * mean;
    float rstd = 1.0f / sqrtf(var + 1e-5f);
    float4 gv = *(const float4*)(g + tid * 4);
    float4 bv = *(const float4*)(bta + tid * 4);
    float4 o;
    o.x = (v.x - mean) * rstd * gv.x + bv.x;
    o.y = (v.y - mean) * rstd * gv.y + bv.y;
    o.z = (v.z - mean) * rstd * gv.z + bv.z;
    o.w = (v.w - mean) * rstd * gv.w + bv.w;
    *(float4*)(x + ((size_t)(b * NT + node_off + n)) * DH + tid * 4) = o;
}

// ---------------- residual + LayerNorm in-place on x ----------------
__global__ __launch_bounds__(256) void ln_residual(
    float* __restrict__ x, const float* __restrict__ o,
    const float* __restrict__ g, const float* __restrict__ bta)
{
    __shared__ float red[256];
    int r = blockIdx.x;
    int tid = threadIdx.x;
    float* xr = x + (size_t)r * DH;
    float4 xv = *(float4*)(xr + tid * 4);
    float4 ov = *(const float4*)(o + (size_t)r * DH + tid * 4);
    float v0 = xv.x + ov.x, v1 = xv.y + ov.y, v2 = xv.z + ov.z, v3 = xv.w + ov.w;
    float s = v0 + v1 + v2 + v3;
    float sq = v0 * v0 + v1 * v1 + v2 * v2 + v3 * v3;
    float tot = block_reduce_sum(s, red);
    float totsq = block_reduce_sum(sq, red);
    float mean = tot * (1.0f / DH);
    float var = totsq * (1.0f / DH) - mean * mean;
    float rstd = 1.0f / sqrtf(var + 1e-5f);
    float4 gv = *(const float4*)(g + tid * 4);
    float4 bv = *(const float4*)(bta + tid * 4);
    float4 out;
    out.x = (v0 - mean) * rstd * gv.x + bv.x;
    out.y = (v1 - mean) * rstd * gv.y + bv.y;
    out.z = (v2 - mean) * rstd * gv.z + bv.z;
    out.w = (v3 - mean) * rstd * gv.w + bv.w;
    *(float4*)(xr + tid * 4) = out;
}

// ---------------- text: masked mean pool of token embeddings ----------------
__global__ __launch_bounds__(256) void pool_kernel(
    const float* __restrict__ tok_emb, const int* __restrict__ ids,
    const int* __restrict__ amask, float* __restrict__ pooled)
{
    int b = blockIdx.x;
    int tid = threadIdx.x;
    float a0 = 0, a1 = 0, a2 = 0, a3 = 0;
    float denom = 0;
    for (int l = 0; l < LQ; ++l) {
        int id = ids[b * LQ + l];
        float m = (float)amask[b * LQ + l];
        denom += m;
        float4 e = *(const float4*)(tok_emb + (size_t)id * DH + tid * 4);
        a0 += m * e.x; a1 += m * e.y; a2 += m * e.z; a3 += m * e.w;
    }
    float inv = 1.0f / fmaxf(denom, 1.0f);
    float4 o = make_float4(a0 * inv, a1 * inv, a2 * inv, a3 * inv);
    *(float4*)(pooled + b * DH + tid * 4) = o;
}

// ---------------- add type embeddings ----------------
__global__ __launch_bounds__(256) void type_add(
    float* __restrict__ x, const int* __restrict__ types,
    const float* __restrict__ type_emb)
{
    int r = blockIdx.x;
    int tid = threadIdx.x;
    int ty = types[r];
    float4 xv = *(float4*)(x + (size_t)r * DH + tid * 4);
    float4 tv = *(const float4*)(type_emb + (size_t)ty * DH + tid * 4);
    xv.x += tv.x; xv.y += tv.y; xv.z += tv.z; xv.w += tv.w;
    *(float4*)(x + (size_t)r * DH + tid * 4) = xv;
}

// ---------------- GAT: s/t head scores, one wave per node row ----------------
__global__ __launch_bounds__(64) void st_kernel(
    const float* __restrict__ hbuf, const float* __restrict__ asrc,
    const float* __restrict__ adst, float* __restrict__ s, float* __restrict__ t)
{
    int r = blockIdx.x;
    int lane = threadIdx.x;
    int b = r >> 10, n = r & 1023;
    const float* hrow = hbuf + (size_t)r * DH;
    for (int h = 0; h < NH; ++h) {
        float2 v = *(const float2*)(hrow + h * DHD + lane * 2);
        float2 s2 = *(const float2*)(asrc + h * DHD + lane * 2);
        float2 t2 = *(const float2*)(adst + h * DHD + lane * 2);
        float ps = v.x * s2.x + v.y * s2.y;
        float pt = v.x * t2.x + v.y * t2.y;
        for (int off = 32; off > 0; off >>= 1) {
            ps += __shfl_down(ps, off, 64);
            pt += __shfl_down(pt, off, 64);
        }
        if (lane == 0) {
            s[(size_t)(b * NH + h) * NT + n] = ps;
            t[(size_t)(b * NH + h) * NT + n] = pt;
        }
    }
}

// ---------------- GAT: masked softmax row stats (bitmask version) ------------
__global__ __launch_bounds__(256) void stats_kernel(
    const unsigned* __restrict__ mb, const float* __restrict__ s,
    const float* __restrict__ t, float* __restrict__ mbuf, float* __restrict__ lbuf)
{
    __shared__ float red[256];
    __shared__ unsigned mwords[32];
    int bi = blockIdx.x;
    int b = bi >> 10, i = bi & 1023;
    int tid = threadIdx.x;
    if (tid < 32) mwords[tid] = mb[(size_t)bi * 32 + tid];
    __syncthreads();
    for (int h = 0; h < NH; ++h) {
        const float* tp = t + (size_t)(b * NH + h) * NT;
        float si = s[(size_t)(b * NH + h) * NT + i];
        float vals[4];
        float mx = -3e38f;
#pragma unroll
        for (int k = 0; k < 4; ++k) {
            int j = tid + k * 256;
            float v = si + tp[j];
            v = v > 0.f ? v : 0.2f * v;
            bool on = (mwords[j >> 5] >> (j & 31)) & 1;
            v = on ? v : -1e9f;
            vals[k] = v;
            mx = fmaxf(mx, v);
        }
        float m = block_reduce_max(mx, red);
        float ls = 0.f;
#pragma unroll
        for (int k = 0; k < 4; ++k) ls += __expf(vals[k] - m);
        float tot = block_reduce_sum(ls, red);
        if (tid == 0) {
            mbuf[(size_t)(b * NH + h) * NT + i] = m;
            lbuf[(size_t)(b * NH + h) * NT + i] = 1.0f / tot;
        }
        __syncthreads();
    }
}

// ---------------- GAT aggregation via MFMA ----------------
// out[b,i,h,:] = sum_j a_ij * h[b,j,h,:].  grid (NT/64, NH, NB), 256 thr.
// A-tile (attention, bf16) [64 i][64 j]; B-tile = ht slice [128 d][64 j].
__global__ __launch_bounds__(256) void agg_mfma(
    const short* __restrict__ ht, const unsigned* __restrict__ mb,
    const float* __restrict__ s, const float* __restrict__ t,
    const float* __restrict__ mbuf, const float* __restrict__ lbuf,
    float* __restrict__ obuf)
{
    __shared__ short vt[128][72];      // [d][j] pad 72 (144B rows -> <=2-way alias)
    __shared__ short at[64][72];       // [i][j]
    __shared__ unsigned mrow[64][32];  // mask bits for i0..i0+63, all 1024 j
    __shared__ float sv[64], mv[64], lv[64];
    int i0 = blockIdx.x * 64;
    int h = blockIdx.y, b = blockIdx.z;
    int tid = threadIdx.x;
    int lane = tid & 63, wave = tid >> 6;
    int quad = lane >> 4, lq = lane & 15;
    int wi = (wave >> 1) * 32;     // wave's i-offset (0 or 32)
    int wd = (wave & 1) * 64;      // wave's d-offset (0 or 64)
    if (tid < 64) {
        size_t idx = (size_t)(b * NH + h) * NT + i0 + tid;
        sv[tid] = s[idx]; mv[tid] = mbuf[idx]; lv[tid] = lbuf[idx];
    }
#pragma unroll
    for (int s2 = 0; s2 < 2; ++s2) {
        int f = tid + s2 * 256;
        int ii = f >> 3, w4 = (f & 7) * 4;
        *(uint4*)&mrow[ii][w4] =
            *(const uint4*)(mb + ((size_t)(b * NT + i0 + ii)) * 32 + w4);
    }
    const float* tptr = t + (size_t)(b * NH + h) * NT;
    const short* hbase = ht + ((size_t)(b * NH + h) * DHD) * NT;
    f32x4 acc[2][4];
#pragma unroll
    for (int i = 0; i < 2; ++i)
#pragma unroll
        for (int j = 0; j < 4; ++j) {
            f32x4 z = {0.f, 0.f, 0.f, 0.f};
            acc[i][j] = z;
        }
    int ii = tid >> 2;             // 0..63 (at row this thread fills)
    int jq = (tid & 3) * 16;       // 16 j's per thread
    for (int j0 = 0; j0 < NT; j0 += 64) {
        __syncthreads();           // protect LDS from previous iter's reads
        // stage vt: 128 d x 64 j bf16
#pragma unroll
        for (int s2 = 0; s2 < 4; ++s2) {
            int f = tid + s2 * 256;
            int d = f >> 3, c = (f & 7) * 8;
            *(short8*)&vt[d][c] = *(const short8*)(hbase + (size_t)d * NT + j0 + c);
        }
        // compute at[ii][jq..jq+15] (fp32 math, bf16 store)
        {
            unsigned mw = mrow[ii][(j0 + jq) >> 5] >> ((j0 + jq) & 31);
            float svv = sv[ii], mvv = mv[ii], lvv = lv[ii];
            float4 t0 = *(const float4*)(tptr + j0 + jq);
            float4 t1 = *(const float4*)(tptr + j0 + jq + 4);
            float4 t2 = *(const float4*)(tptr + j0 + jq + 8);
            float4 t3 = *(const float4*)(tptr + j0 + jq + 12);
            float tv16[16] = {t0.x, t0.y, t0.z, t0.w, t1.x, t1.y, t1.z, t1.w,
                              t2.x, t2.y, t2.z, t2.w, t3.x, t3.y, t3.z, t3.w};
            short8 p0, p1;
#pragma unroll
            for (int e = 0; e < 8; ++e) {
                float v = svv + tv16[e];
                v = v > 0.f ? v : 0.2f * v;
                float a = ((mw >> e) & 1) ? __expf(v - mvv) * lvv : 0.f;
                p0[e] = f2bf(a);
            }
#pragma unroll
            for (int e = 0; e < 8; ++e) {
                float v = svv + tv16[8 + e];
                v = v > 0.f ? v : 0.2f * v;
                float a = ((mw >> (8 + e)) & 1) ? __expf(v - mvv) * lvv : 0.f;
                p1[e] = f2bf(a);
            }
            *(short8*)&at[ii][jq] = p0;
            *(short8*)&at[ii][jq + 8] = p1;
        }
        __syncthreads();
        // MFMA over this j-tile: 2 k-steps of 32
#pragma unroll
        for (int ks = 0; ks < 2; ++ks) {
            short8 af[2], bfr[4];
            af[0] = *(short8*)&at[wi + lq][ks * 32 + quad * 8];
            af[1] = *(short8*)&at[wi + 16 + lq][ks * 32 + quad * 8];
#pragma unroll
            for (int j = 0; j < 4; ++j)
                bfr[j] = *(short8*)&vt[wd + j * 16 + lq][ks * 32 + quad * 8];
#pragma unroll
            for (int i2 = 0; i2 < 2; ++i2)
#pragma unroll
                for (int j = 0; j < 4; ++j)
                    acc[i2][j] = __builtin_amdgcn_mfma_f32_16x16x32_bf16(
                        af[i2], bfr[j], acc[i2][j], 0, 0, 0);
        }
    }
    // epilogue: i = i0+wi+i2*16+quad*4+r, d = wd + j*16 + lq
#pragma unroll
    for (int i2 = 0; i2 < 2; ++i2) {
#pragma unroll
        for (int r = 0; r < 4; ++r) {
            int i = i0 + wi + i2 * 16 + quad * 4 + r;
            float* dst = obuf + ((size_t)(b * NT + i)) * DH + h * DHD + wd;
#pragma unroll
            for (int j = 0; j < 4; ++j)
                dst[j * 16 + lq] = acc[i2][j][r];
        }
    }
}

// ---------------- readout scores: one wave per node ----------------
__global__ __launch_bounds__(64) void score_kernel(
    const float* __restrict__ x, const float* __restrict__ rW,
    const float* __restrict__ rb, float* __restrict__ scores)
{
    int r = blockIdx.x;
    int lane = threadIdx.x;
    const float* xr = x + (size_t)r * DH;
    float acc = 0.f;
#pragma unroll
    for (int k = 0; k < 4; ++k) {
        float4 xv = *(const float4*)(xr + lane * 16 + k * 4);
        float4 wv = *(const float4*)(rW + lane * 16 + k * 4);
        acc += xv.x * wv.x + xv.y * wv.y + xv.z * wv.z + xv.w * wv.w;
    }
    for (int off = 32; off > 0; off >>= 1) acc += __shfl_down(acc, off, 64);
    if (lane == 0) scores[r] = acc + rb[0];
}

// ---------------- per-batch softmax over node scores (in place) ----------------
__global__ __launch_bounds__(256) void softmax_w(float* __restrict__ scores)
{
    __shared__ float red[256];
    int b = blockIdx.x;
    int tid = threadIdx.x;
    float* sr = scores + (size_t)b * NT;
    float v[4];
    float mx = -3e38f;
#pragma unroll
    for (int k = 0; k < 4; ++k) { v[k] = sr[tid + k * 256]; mx = fmaxf(mx, v[k]); }
    float m = block_reduce_max(mx, red);
    float ls = 0.f;
#pragma unroll
    for (int k = 0; k < 4; ++k) { v[k] = expf(v[k] - m); ls += v[k]; }
    float tot = block_reduce_sum(ls, red);
    float inv = 1.0f / tot;
#pragma unroll
    for (int k = 0; k < 4; ++k) sr[tid + k * 256] = v[k] * inv;
}

// ---------------- weighted pool partials ----------------
__global__ __launch_bounds__(256) void pool_part(
    const float* __restrict__ x, const float* __restrict__ w,
    float* __restrict__ gpart)
{
    int p = blockIdx.x;
    int b = blockIdx.y;
    int tid = threadIdx.x;
    float a0 = 0, a1 = 0, a2 = 0, a3 = 0;
    for (int n = p * 128; n < (p + 1) * 128; ++n) {
        float wv = w[(size_t)b * NT + n];
        float4 xv = *(const float4*)(x + ((size_t)(b * NT + n)) * DH + tid * 4);
        a0 += wv * xv.x; a1 += wv * xv.y; a2 += wv * xv.z; a3 += wv * xv.w;
    }
    float4 o = make_float4(a0, a1, a2, a3);
    *(float4*)(gpart + ((size_t)(b * 8 + p)) * DH + tid * 4) = o;
}

// ---------------- final candidate scorer ----------------
__global__ __launch_bounds__(256) void scorer_kernel(
    const float* __restrict__ gpart, const float* __restrict__ W1,
    const float* __restrict__ b1, const float* __restrict__ W2,
    const float* __restrict__ b2, float* __restrict__ out)
{
    __shared__ float gsh[DH];
    __shared__ float red[256];
    int b = blockIdx.x;
    int tid = threadIdx.x;
#pragma unroll
    for (int c = 0; c < 4; ++c) {
        int d = tid + c * 256;
        float gv = 0.f;
        for (int p = 0; p < 8; ++p) gv += gpart[((size_t)(b * 8 + p)) * DH + d];
        gsh[d] = gv;
    }
    __syncthreads();
    float acc[4] = {};
    for (int d = 0; d < DH; ++d) {
        float gv = gsh[d];
        const float* wr = W1 + (size_t)d * DH;
#pragma unroll
        for (int c = 0; c < 4; ++c) acc[c] += gv * wr[tid + c * 256];
    }
    float part = 0.f;
#pragma unroll
    for (int c = 0; c < 4; ++c) {
        int k = tid + c * 256;
        float u = acc[c] + b1[k];
        float inner = 0.7978845608028654f * (u + 0.044715f * u * u * u);
        float gel = 0.5f * u * (1.0f + tanhf(inner));
        part += gel * W2[k];
    }
    float tot = block_reduce_sum(part, red);
    if (tid == 0) out[b] = tot + b2[0];
}

// ---------------- launch ----------------
extern "C" void kernel_launch(void* const* d_in, const int* in_sizes, int n_in,
                              void* d_out, int out_size, void* d_ws, size_t ws_size,
                              hipStream_t stream)
{
    const float* visual   = (const float*)d_in[0];
    const int*   q_ids    = (const int*)d_in[1];
    const int*   q_mask   = (const int*)d_in[2];
    const float* kg_feat  = (const float*)d_in[3];
    const int*   adj      = (const int*)d_in[4];
    const int*   ntypes   = (const int*)d_in[5];
    const float* vis_W    = (const float*)d_in[6];
    const float* vis_b    = (const float*)d_in[7];
    const float* vis_lng  = (const float*)d_in[8];
    const float* vis_lnb  = (const float*)d_in[9];
    const float* tok_emb  = (const float*)d_in[10];
    const float* q_W      = (const float*)d_in[11];
    const float* q_b      = (const float*)d_in[12];
    const float* q_lng    = (const float*)d_in[13];
    const float* q_lnb    = (const float*)d_in[14];
    const float* kg_W     = (const float*)d_in[15];
    const float* kg_b     = (const float*)d_in[16];
    const float* kg_lng   = (const float*)d_in[17];
    const float* kg_lnb   = (const float*)d_in[18];
    const float* type_emb = (const float*)d_in[19];
    const float* gat_W    = (const float*)d_in[20];
    const float* gat_b    = (const float*)d_in[21];
    const float* a_src    = (const float*)d_in[22];
    const float* a_dst    = (const float*)d_in[23];
    const float* gat_lng  = (const float*)d_in[24];
    const float* gat_lnb  = (const float*)d_in[25];
    const float* read_W   = (const float*)d_in[26];
    const float* read_b   = (const float*)d_in[27];
    const float* cs_W1    = (const float*)d_in[28];
    const float* cs_b1    = (const float*)d_in[29];
    const float* cs_W2    = (const float*)d_in[30];
    const float* cs_b2    = (const float*)d_in[31];
    float* out = (float*)d_out;

    float* ws = (float*)d_ws;
    const size_t NROW = (size_t)NB * NT;
    float* x      = ws;                       // 8M floats
    float* hbuf   = x + NROW * DH;            // 8M floats
    float* obuf   = hbuf + NROW * DH;         // 8M floats (also proj GEMM temp)
    float* sbuf   = obuf + NROW * DH;
    float* tbuf   = sbuf + NB * NH * NT;
    float* mbuf   = tbuf + NB * NH * NT;
    float* lbuf   = mbuf + NB * NH * NT;
    float* pooled = lbuf + NB * NH * NT;
    float* scores = pooled + NB * DH;
    float* gpart  = scores + NROW;
    short* wt_gat = (short*)(gpart + NB * 8 * DH);          // 3 x 1M shorts (6 MB)
    short* ht     = wt_gat + (size_t)NLAYERS * DH * DH;     // 8M shorts (16 MB)
    unsigned* mb  = (unsigned*)(ht + (size_t)NB * NH * DHD * NT); // 256K u32 (1 MB)
    // projection weights (dead before first hbuf write) alias into hbuf
    short* wt_vis = (short*)hbuf;                           // 1024x2048
    short* wt_q   = wt_vis + (size_t)1024 * 2048;           // 1024x1024
    short* wt_kg  = wt_q + (size_t)1024 * 1024;             // 1024x320

    // 0. weight transpose-casts + adjacency bitmask
    transpose_cast<<<dim3(16, 32), 256, 0, stream>>>(vis_W, wt_vis, DV, DH, DV);
    transpose_cast<<<dim3(16, 16), 256, 0, stream>>>(q_W, wt_q, DH, DH, DH);
    transpose_cast<<<dim3(16, 5), 256, 0, stream>>>(kg_W, wt_kg, DK, DH, 320);
    for (int l = 0; l < NLAYERS; ++l)
        transpose_cast<<<dim3(16, 16), 256, 0, stream>>>(
            gat_W + (size_t)l * DH * DH, wt_gat + (size_t)l * DH * DH, DH, DH, DH);
    bitmask_kernel<<<NB * NT, 256, 0, stream>>>(adj, mb);

    // 1. visual projection + LN -> x[:, 0:100]
    gemm_bias_mfma<<<dim3(8, 7), 256, 0, stream>>>(
        visual, wt_vis, vis_b, obuf, NB * NV, DH, DV, DV, DV);
    ln_scatter<<<NB * NV, 256, 0, stream>>>(obuf, x, vis_lng, vis_lnb, NB * NV, NV, 0);

    // 2. text pool + proj + LN -> x[:, 100]
    pool_kernel<<<NB, 256, 0, stream>>>(tok_emb, q_ids, q_mask, pooled);
    gemm_bias_mfma<<<dim3(8, 1), 256, 0, stream>>>(
        pooled, wt_q, q_b, obuf, NB, DH, DH, DH, DH);
    ln_scatter<<<NB, 256, 0, stream>>>(obuf, x, q_lng, q_lnb, NB, 1, NV);

    // 3. KG projection + LN -> x[:, 101:1024]
    gemm_bias_mfma<<<dim3(8, 58), 256, 0, stream>>>(
        kg_feat, wt_kg, kg_b, obuf, NB * NKG, DH, DK, 320, DK);
    ln_scatter<<<NB * NKG, 256, 0, stream>>>(obuf, x, kg_lng, kg_lnb, NB * NKG, NKG, NV + 1);

    // 4. + type embeddings
    type_add<<<NB * NT, 256, 0, stream>>>(x, ntypes, type_emb);

    // 5. GAT layers
    for (int l = 0; l < NLAYERS; ++l) {
        const float* bl  = gat_b + (size_t)l * DH;
        const float* asl = a_src + (size_t)l * NH * DHD;
        const float* adl = a_dst + (size_t)l * NH * DHD;
        gemm_bias_mfma<<<dim3(8, 64), 256, 0, stream>>>(
            x, wt_gat + (size_t)l * DH * DH, bl, hbuf, NB * NT, DH, DH, DH, DH);
        st_kernel<<<NB * NT, 64, 0, stream>>>(hbuf, asl, adl, sbuf, tbuf);
        transpose_h<<<dim3(16, 2, NB * NH), 256, 0, stream>>>(hbuf, ht);
        stats_kernel<<<NB * NT, 256, 0, stream>>>(mb, sbuf, tbuf, mbuf, lbuf);
        agg_mfma<<<dim3(16, NH, NB), 256, 0, stream>>>(
            ht, mb, sbuf, tbuf, mbuf, lbuf, obuf);
        ln_residual<<<NB * NT, 256, 0, stream>>>(x, obuf,
            gat_lng + (size_t)l * DH, gat_lnb + (size_t)l * DH);
    }

    // 6. readout + scorer
    score_kernel<<<NB * NT, 64, 0, stream>>>(x, read_W, read_b, scores);
    softmax_w<<<NB, 256, 0, stream>>>(scores);
    pool_part<<<dim3(8, NB), 256, 0, stream>>>(x, scores, gpart);
    scorer_kernel<<<NB, 256, 0, stream>>>(gpart, cs_W1, cs_b1, cs_W2, cs_b2, out);
}

// Round 5
// 1095.988 us; speedup vs baseline: 3.0059x; 1.2411x over previous
//
#include <hip/hip_runtime.h>
#include <math.h>

#define NB 8
#define NV 100
#define LQ 128
#define NKG 923
#define NT 1024
#define DV 2048
#define DK 300
#define DH 1024
#define NH 8
#define DHD 128
#define NLAYERS 3

typedef __attribute__((ext_vector_type(8))) short short8;
typedef __attribute__((ext_vector_type(4))) float f32x4;

__device__ __forceinline__ short f2bf(float f) {
    unsigned u = __float_as_uint(f);
    u += 0x7fff + ((u >> 16) & 1);   // round-to-nearest-even
    return (short)(u >> 16);
}
__device__ __forceinline__ float bf2f(short s) {
    unsigned u = ((unsigned)(unsigned short)s) << 16;
    return __uint_as_float(u);
}
__device__ __forceinline__ unsigned pack2(float a, float b) {
    return (unsigned)(unsigned short)f2bf(a) | ((unsigned)(unsigned short)f2bf(b) << 16);
}

// async 16B global->LDS (lane dst = wave-uniform base + lane*16)
#if __has_builtin(__builtin_amdgcn_global_load_lds)
#define HAVE_GLL 1
__device__ __forceinline__ void gll16(const void* g, void* l) {
    __builtin_amdgcn_global_load_lds(
        (const __attribute__((address_space(1))) void*)g,
        (__attribute__((address_space(3))) void*)l, 16, 0, 0);
}
#else
#define HAVE_GLL 0
#endif

// ---------------- block reduce helpers (blockDim.x == 256) ----------------
__device__ __forceinline__ float block_reduce_sum(float v, float* red) {
    int tid = threadIdx.x;
    red[tid] = v; __syncthreads();
    for (int s = 128; s > 0; s >>= 1) {
        if (tid < s) red[tid] += red[tid + s];
        __syncthreads();
    }
    float r = red[0]; __syncthreads();
    return r;
}
__device__ __forceinline__ float block_reduce_max(float v, float* red) {
    int tid = threadIdx.x;
    red[tid] = v; __syncthreads();
    for (int s = 128; s > 0; s >>= 1) {
        if (tid < s) red[tid] = fmaxf(red[tid], red[tid + s]);
        __syncthreads();
    }
    float r = red[0]; __syncthreads();
    return r;
}

// ---------------- adjacency -> bitmask ----------------
__global__ __launch_bounds__(256) void bitmask_kernel(
    const int* __restrict__ adj, unsigned* __restrict__ mb)
{
    int bi = blockIdx.x;
    int tid = threadIdx.x;
#pragma unroll
    for (int p = 0; p < 4; ++p) {
        int j = p * 256 + tid;
        unsigned long long bal = __ballot(adj[(size_t)bi * NT + j] > 0);
        if ((tid & 63) == 0) {
            int w = (p * 256 + (tid & 0xC0)) >> 5;
            mb[(size_t)bi * 32 + w]     = (unsigned)bal;
            mb[(size_t)bi * 32 + w + 1] = (unsigned)(bal >> 32);
        }
    }
}

// ---------------- weight transpose-cast: out[N,Kp] bf16 <- in[K,N] fp32 ----
__global__ __launch_bounds__(256) void transpose_cast(
    const float* __restrict__ in, short* __restrict__ out,
    int K, int N, int Kp)
{
    __shared__ float ls[64][65];
    int n0 = blockIdx.x * 64, k0 = blockIdx.y * 64;
    int tid = threadIdx.x;
    int j4 = (tid & 15) * 4;
#pragma unroll
    for (int s = 0; s < 4; ++s) {
        int i = (tid >> 4) + s * 16;
        int k = k0 + i;
        float4 v = make_float4(0.f, 0.f, 0.f, 0.f);
        if (k < K) v = *(const float4*)(in + (size_t)k * N + n0 + j4);
        ls[i][j4 + 0] = v.x; ls[i][j4 + 1] = v.y;
        ls[i][j4 + 2] = v.z; ls[i][j4 + 3] = v.w;
    }
    __syncthreads();
#pragma unroll
    for (int s = 0; s < 4; ++s) {
        int a = (tid >> 4) + s * 16;
        int b = (tid & 15) * 4;
        uint2 pk;
        pk.x = pack2(ls[b + 0][a], ls[b + 1][a]);
        pk.y = pack2(ls[b + 2][a], ls[b + 3][a]);
        *(uint2*)(out + (size_t)(n0 + a) * Kp + k0 + b) = pk;
    }
}

// ---------------- MFMA GEMM (fp32 A): C = A @ Wt^T + bias  (projections) ---
__global__ __launch_bounds__(256) void gemm_bias_mfma(
    const float* __restrict__ A, const short* __restrict__ Wt,
    const float* __restrict__ bias, float* __restrict__ C,
    int M, int N, int K, int Kp, int ldA)
{
    __shared__ short At[128][32];
    __shared__ short Bt[128][32];
    int tid = threadIdx.x;
    int row0 = blockIdx.y * 128, col0 = blockIdx.x * 128;
    int lane = tid & 63, wave = tid >> 6;
    int quad = lane >> 4, lq = lane & 15;
    int wm = (wave >> 1) * 64, wn = (wave & 1) * 64;
    f32x4 acc[4][4];
#pragma unroll
    for (int i = 0; i < 4; ++i)
#pragma unroll
        for (int j = 0; j < 4; ++j) {
            f32x4 z = {0.f, 0.f, 0.f, 0.f};
            acc[i][j] = z;
        }
    int ar = tid >> 2;
    int ac = (tid & 3) * 8;
    for (int k0 = 0; k0 < Kp; k0 += 32) {
        bool fullk = (k0 + 32 <= K);
#pragma unroll
        for (int s = 0; s < 2; ++s) {
            int r = ar + s * 64;
            int grow = row0 + r;
            short8 pk;
            if (grow < M && fullk) {
                const float* src = A + (size_t)grow * ldA + k0 + ac;
                float4 v0 = *(const float4*)(src);
                float4 v1 = *(const float4*)(src + 4);
                pk[0] = f2bf(v0.x); pk[1] = f2bf(v0.y);
                pk[2] = f2bf(v0.z); pk[3] = f2bf(v0.w);
                pk[4] = f2bf(v1.x); pk[5] = f2bf(v1.y);
                pk[6] = f2bf(v1.z); pk[7] = f2bf(v1.w);
            } else {
#pragma unroll
                for (int e = 0; e < 8; ++e) {
                    int k = k0 + ac + e;
                    pk[e] = (grow < M && k < K)
                          ? f2bf(A[(size_t)grow * ldA + k]) : (short)0;
                }
            }
            *(short8*)&At[r][ac] = pk;
        }
#pragma unroll
        for (int s = 0; s < 2; ++s) {
            int n = ar + s * 64;
            short8 w = *(const short8*)(Wt + (size_t)(col0 + n) * Kp + k0 + ac);
            *(short8*)&Bt[n][ac] = w;
        }
        __syncthreads();
        short8 af[4], bfr[4];
#pragma unroll
        for (int i = 0; i < 4; ++i)
            af[i] = *(short8*)&At[wm + i * 16 + lq][quad * 8];
#pragma unroll
        for (int j = 0; j < 4; ++j)
            bfr[j] = *(short8*)&Bt[wn + j * 16 + lq][quad * 8];
#pragma unroll
        for (int i = 0; i < 4; ++i)
#pragma unroll
            for (int j = 0; j < 4; ++j)
                acc[i][j] = __builtin_amdgcn_mfma_f32_16x16x32_bf16(
                    af[i], bfr[j], acc[i][j], 0, 0, 0);
        __syncthreads();
    }
#pragma unroll
    for (int j = 0; j < 4; ++j) {
        int n = col0 + wn + j * 16 + lq;
        float bv = bias[n];
#pragma unroll
        for (int i = 0; i < 4; ++i) {
#pragma unroll
            for (int r = 0; r < 4; ++r) {
                int m = row0 + wm + i * 16 + quad * 4 + r;
                if (m < M) C[(size_t)m * N + n] = acc[i][j][r] + bv;
            }
        }
    }
}

// ---------------- fused GAT gemm: h = xb@W^T+b, writes ht (bf16 [d][j]) + s,t
// grid (NH, M/128). col block == head (DHD==128). M,K multiples of 128/32.
__global__ __launch_bounds__(256) void gemm_st_mfma(
    const short* __restrict__ Ab,      // xb [M][DH] bf16
    const short* __restrict__ Wt,      // [DH][DH] bf16 (n-major, k contig)
    const float* __restrict__ bias,
    const float* __restrict__ asrc,    // [NH*DHD] this layer
    const float* __restrict__ adst,
    short* __restrict__ ht,            // [(b*NH+h)*DHD + d][NT]
    float* __restrict__ sbuf, float* __restrict__ tbuf)
{
    __shared__ short At[128][32];
    __shared__ short Bt[128][32];
    __shared__ short ct[128][136];     // [d][i] bf16, 272B rows (16B-aligned)
    __shared__ float sred[2][128], tred[2][128];
    __shared__ float asl[128], adl[128];
    int tid = threadIdx.x;
    int h = blockIdx.x;
    int row0 = blockIdx.y * 128, col0 = h * 128;
    int b = row0 >> 10, i0 = row0 & 1023;
    int lane = tid & 63, wave = tid >> 6;
    int quad = lane >> 4, lq = lane & 15;
    int wm = (wave >> 1) * 64, wn = (wave & 1) * 64;
    if (tid < 128) asl[tid] = asrc[h * DHD + tid];
    else adl[tid - 128] = adst[h * DHD + tid - 128];
    f32x4 acc[4][4];
#pragma unroll
    for (int i = 0; i < 4; ++i)
#pragma unroll
        for (int j = 0; j < 4; ++j) {
            f32x4 z = {0.f, 0.f, 0.f, 0.f};
            acc[i][j] = z;
        }

    const short* gA0 = Ab + (size_t)(row0 + wave * 16 + (lane >> 2)) * DH + (lane & 3) * 8;
    const short* gA1 = gA0 + (size_t)64 * DH;
    const short* gB0 = Wt + (size_t)(col0 + wave * 16 + (lane >> 2)) * DH + (lane & 3) * 8;
    const short* gB1 = gB0 + (size_t)64 * DH;
#if HAVE_GLL
    char* lA0 = (char*)At + wave * 1024; char* lA1 = lA0 + 4096;
    char* lB0 = (char*)Bt + wave * 1024; char* lB1 = lB0 + 4096;
#endif
    for (int k0 = 0; k0 < DH; k0 += 32) {
#if HAVE_GLL
        gll16(gA0 + k0, lA0); gll16(gA1 + k0, lA1);
        gll16(gB0 + k0, lB0); gll16(gB1 + k0, lB1);
#else
        {
            short8 va0 = *(const short8*)(gA0 + k0);
            short8 va1 = *(const short8*)(gA1 + k0);
            short8 vb0 = *(const short8*)(gB0 + k0);
            short8 vb1 = *(const short8*)(gB1 + k0);
            *(short8*)((char*)At + wave * 1024 + lane * 16) = va0;
            *(short8*)((char*)At + 4096 + wave * 1024 + lane * 16) = va1;
            *(short8*)((char*)Bt + wave * 1024 + lane * 16) = vb0;
            *(short8*)((char*)Bt + 4096 + wave * 1024 + lane * 16) = vb1;
        }
#endif
        __syncthreads();
        short8 af[4], bfr[4];
#pragma unroll
        for (int i = 0; i < 4; ++i)
            af[i] = *(short8*)&At[wm + i * 16 + lq][quad * 8];
#pragma unroll
        for (int j = 0; j < 4; ++j)
            bfr[j] = *(short8*)&Bt[wn + j * 16 + lq][quad * 8];
#pragma unroll
        for (int i = 0; i < 4; ++i)
#pragma unroll
            for (int j = 0; j < 4; ++j)
                acc[i][j] = __builtin_amdgcn_mfma_f32_16x16x32_bf16(
                    af[i], bfr[j], acc[i][j], 0, 0, 0);
        __syncthreads();
    }
    // epilogue 1: bias + bf16, store transposed tile ct[d][i]
#pragma unroll
    for (int j = 0; j < 4; ++j) {
        int d = wn + j * 16 + lq;
        float bv = bias[col0 + d];
#pragma unroll
        for (int i2 = 0; i2 < 4; ++i2) {
            int m = wm + i2 * 16 + quad * 4;
            uint2 pk;
            pk.x = pack2(acc[i2][j][0] + bv, acc[i2][j][1] + bv);
            pk.y = pack2(acc[i2][j][2] + bv, acc[i2][j][3] + bv);
            *(uint2*)&ct[d][m] = pk;
        }
    }
    __syncthreads();
    // epilogue 2: ht global store (b128 rows of ct)
    {
        int d = tid >> 1, half = tid & 1;
        short* dst = ht + ((size_t)(b * NH + h) * DHD + d) * NT + i0 + half * 64;
        const short* src = &ct[d][half * 64];
#pragma unroll
        for (int q = 0; q < 8; ++q)
            *(short8*)(dst + q * 8) = *(const short8*)(src + q * 8);
    }
    // epilogue 3: s,t from ct
    {
        int i = tid >> 1, half = tid & 1;
        float sa = 0.f, ta = 0.f;
#pragma unroll 16
        for (int dd = 0; dd < 64; ++dd) {
            int d = half * 64 + dd;
            float hv = bf2f(ct[d][i]);
            sa += hv * asl[d];
            ta += hv * adl[d];
        }
        sred[half][i] = sa; tred[half][i] = ta;
    }
    __syncthreads();
    if (tid < 128) {
        size_t idx = (size_t)(b * NH + h) * NT + i0 + tid;
        sbuf[idx] = sred[0][tid] + sred[1][tid];
        tbuf[idx] = tred[0][tid] + tred[1][tid];
    }
}

// ---------------- LayerNorm + scatter into x ----------------
__global__ __launch_bounds__(256) void ln_scatter(
    const float* __restrict__ src, float* __restrict__ x,
    const float* __restrict__ g, const float* __restrict__ bta,
    int rows, int npb, int node_off)
{
    __shared__ float red[256];
    int r = blockIdx.x;
    if (r >= rows) return;
    int tid = threadIdx.x;
    int b = r / npb, n = r % npb;
    float4 v = *(const float4*)(src + (size_t)r * DH + tid * 4);
    float s = v.x + v.y + v.z + v.w;
    float sq = v.x * v.x + v.y * v.y + v.z * v.z + v.w * v.w;
    float tot = block_reduce_sum(s, red);
    float totsq = block_reduce_sum(sq, red);
    float mean = tot * (1.0f / DH);
    float var = totsq * (1.0f / DH) - mean * mean;
    float rstd = 1.0f / sqrtf(var + 1e-5f);
    float4 gv = *(const float4*)(g + tid * 4);
    float4 bv = *(const float4*)(bta + tid * 4);
    float4 o;
    o.x = (v.x - mean) * rstd * gv.x + bv.x;
    o.y = (v.y - mean) * rstd * gv.y + bv.y;
    o.z = (v.z - mean) * rstd * gv.z + bv.z;
    o.w = (v.w - mean) * rstd * gv.w + bv.w;
    *(float4*)(x + ((size_t)(b * NT + node_off + n)) * DH + tid * 4) = o;
}

// ---------------- residual + LayerNorm in-place, also writes bf16 copy ------
__global__ __launch_bounds__(256) void ln_residual(
    float* __restrict__ x, const float* __restrict__ o,
    const float* __restrict__ g, const float* __restrict__ bta,
    short* __restrict__ xb)
{
    __shared__ float red[256];
    int r = blockIdx.x;
    int tid = threadIdx.x;
    float* xr = x + (size_t)r * DH;
    float4 xv = *(float4*)(xr + tid * 4);
    float4 ov = *(const float4*)(o + (size_t)r * DH + tid * 4);
    float v0 = xv.x + ov.x, v1 = xv.y + ov.y, v2 = xv.z + ov.z, v3 = xv.w + ov.w;
    float s = v0 + v1 + v2 + v3;
    float sq = v0 * v0 + v1 * v1 + v2 * v2 + v3 * v3;
    float tot = block_reduce_sum(s, red);
    float totsq = block_reduce_sum(sq, red);
    float mean = tot * (1.0f / DH);
    float var = totsq * (1.0f / DH) - mean * mean;
    float rstd = 1.0f / sqrtf(var + 1e-5f);
    float4 gv = *(const float4*)(g + tid * 4);
    float4 bv = *(const float4*)(bta + tid * 4);
    float4 out;
    out.x = (v0 - mean) * rstd * gv.x + bv.x;
    out.y = (v1 - mean) * rstd * gv.y + bv.y;
    out.z = (v2 - mean) * rstd * gv.z + bv.z;
    out.w = (v3 - mean) * rstd * gv.w + bv.w;
    *(float4*)(xr + tid * 4) = out;
    uint2 pk;
    pk.x = pack2(out.x, out.y);
    pk.y = pack2(out.z, out.w);
    *(uint2*)(xb + (size_t)r * DH + tid * 4) = pk;
}

// ---------------- text: masked mean pool ----------------
__global__ __launch_bounds__(256) void pool_kernel(
    const float* __restrict__ tok_emb, const int* __restrict__ ids,
    const int* __restrict__ amask, float* __restrict__ pooled)
{
    int b = blockIdx.x;
    int tid = threadIdx.x;
    float a0 = 0, a1 = 0, a2 = 0, a3 = 0;
    float denom = 0;
    for (int l = 0; l < LQ; ++l) {
        int id = ids[b * LQ + l];
        float m = (float)amask[b * LQ + l];
        denom += m;
        float4 e = *(const float4*)(tok_emb + (size_t)id * DH + tid * 4);
        a0 += m * e.x; a1 += m * e.y; a2 += m * e.z; a3 += m * e.w;
    }
    float inv = 1.0f / fmaxf(denom, 1.0f);
    float4 o = make_float4(a0 * inv, a1 * inv, a2 * inv, a3 * inv);
    *(float4*)(pooled + b * DH + tid * 4) = o;
}

// ---------------- add type embeddings, write x and xb ----------------
__global__ __launch_bounds__(256) void type_add(
    float* __restrict__ x, const int* __restrict__ types,
    const float* __restrict__ type_emb, short* __restrict__ xb)
{
    int r = blockIdx.x;
    int tid = threadIdx.x;
    int ty = types[r];
    float4 xv = *(float4*)(x + (size_t)r * DH + tid * 4);
    float4 tv = *(const float4*)(type_emb + (size_t)ty * DH + tid * 4);
    xv.x += tv.x; xv.y += tv.y; xv.z += tv.z; xv.w += tv.w;
    *(float4*)(x + (size_t)r * DH + tid * 4) = xv;
    uint2 pk;
    pk.x = pack2(xv.x, xv.y);
    pk.y = pack2(xv.z, xv.w);
    *(uint2*)(xb + (size_t)r * DH + tid * 4) = pk;
}

// ---------------- masked softmax row stats: wave per 2 heads, no barriers ---
__global__ __launch_bounds__(256) void stats_kernel(
    const unsigned* __restrict__ mb, const float* __restrict__ s,
    const float* __restrict__ t, float* __restrict__ mbuf, float* __restrict__ lbuf)
{
    __shared__ unsigned mwords[32];
    int bi = blockIdx.x;
    int b = bi >> 10, i = bi & 1023;
    int tid = threadIdx.x;
    int wave = tid >> 6, lane = tid & 63;
    if (tid < 32) mwords[tid] = mb[(size_t)bi * 32 + tid];
    __syncthreads();
#pragma unroll
    for (int hh = 0; hh < 2; ++hh) {
        int h = wave * 2 + hh;
        const float* tp = t + (size_t)(b * NH + h) * NT;
        float si = s[(size_t)(b * NH + h) * NT + i];
        float vals[16];
        float mx = -3e38f;
#pragma unroll
        for (int k = 0; k < 16; ++k) {
            int j = k * 64 + lane;
            float v = si + tp[j];
            v = v > 0.f ? v : 0.2f * v;
            bool on = (mwords[j >> 5] >> (j & 31)) & 1;
            v = on ? v : -1e9f;
            vals[k] = v;
            mx = fmaxf(mx, v);
        }
#pragma unroll
        for (int off = 32; off > 0; off >>= 1)
            mx = fmaxf(mx, __shfl_xor(mx, off, 64));
        float ls = 0.f;
#pragma unroll
        for (int k = 0; k < 16; ++k) ls += __expf(vals[k] - mx);
#pragma unroll
        for (int off = 32; off > 0; off >>= 1)
            ls += __shfl_xor(ls, off, 64);
        if (lane == 0) {
            mbuf[(size_t)(b * NH + h) * NT + i] = mx;
            lbuf[(size_t)(b * NH + h) * NT + i] = 1.0f / ls;
        }
    }
}

// ---------------- GAT aggregation via MFMA ----------------
__global__ __launch_bounds__(256) void agg_mfma(
    const short* __restrict__ ht, const unsigned* __restrict__ mb,
    const float* __restrict__ s, const float* __restrict__ t,
    const float* __restrict__ mbuf, const float* __restrict__ lbuf,
    float* __restrict__ obuf)
{
    __shared__ short vt[128][72];
    __shared__ short at[64][72];
    __shared__ unsigned mrow[64][32];
    __shared__ float sv[64], mv[64], lv[64];
    int i0 = blockIdx.x * 64;
    int h = blockIdx.y, b = blockIdx.z;
    int tid = threadIdx.x;
    int lane = tid & 63, wave = tid >> 6;
    int quad = lane >> 4, lq = lane & 15;
    int wi = (wave >> 1) * 32;
    int wd = (wave & 1) * 64;
    if (tid < 64) {
        size_t idx = (size_t)(b * NH + h) * NT + i0 + tid;
        sv[tid] = s[idx]; mv[tid] = mbuf[idx]; lv[tid] = lbuf[idx];
    }
#pragma unroll
    for (int s2 = 0; s2 < 2; ++s2) {
        int f = tid + s2 * 256;
        int ii = f >> 3, w4 = (f & 7) * 4;
        *(uint4*)&mrow[ii][w4] =
            *(const uint4*)(mb + ((size_t)(b * NT + i0 + ii)) * 32 + w4);
    }
    const float* tptr = t + (size_t)(b * NH + h) * NT;
    const short* hbase = ht + ((size_t)(b * NH + h) * DHD) * NT;
    f32x4 acc[2][4];
#pragma unroll
    for (int i = 0; i < 2; ++i)
#pragma unroll
        for (int j = 0; j < 4; ++j) {
            f32x4 z = {0.f, 0.f, 0.f, 0.f};
            acc[i][j] = z;
        }
    int ii = tid >> 2;
    int jq = (tid & 3) * 16;
    for (int j0 = 0; j0 < NT; j0 += 64) {
        __syncthreads();
#pragma unroll
        for (int s2 = 0; s2 < 4; ++s2) {
            int f = tid + s2 * 256;
            int d = f >> 3, c = (f & 7) * 8;
            *(short8*)&vt[d][c] = *(const short8*)(hbase + (size_t)d * NT + j0 + c);
        }
        {
            unsigned mw = mrow[ii][(j0 + jq) >> 5] >> ((j0 + jq) & 31);
            float svv = sv[ii], mvv = mv[ii], lvv = lv[ii];
            float4 t0 = *(const float4*)(tptr + j0 + jq);
            float4 t1 = *(const float4*)(tptr + j0 + jq + 4);
            float4 t2 = *(const float4*)(tptr + j0 + jq + 8);
            float4 t3 = *(const float4*)(tptr + j0 + jq + 12);
            float tv16[16] = {t0.x, t0.y, t0.z, t0.w, t1.x, t1.y, t1.z, t1.w,
                              t2.x, t2.y, t2.z, t2.w, t3.x, t3.y, t3.z, t3.w};
            short8 p0, p1;
#pragma unroll
            for (int e = 0; e < 8; ++e) {
                float v = svv + tv16[e];
                v = v > 0.f ? v : 0.2f * v;
                float a = ((mw >> e) & 1) ? __expf(v - mvv) * lvv : 0.f;
                p0[e] = f2bf(a);
            }
#pragma unroll
            for (int e = 0; e < 8; ++e) {
                float v = svv + tv16[8 + e];
                v = v > 0.f ? v : 0.2f * v;
                float a = ((mw >> (8 + e)) & 1) ? __expf(v - mvv) * lvv : 0.f;
                p1[e] = f2bf(a);
            }
            *(short8*)&at[ii][jq] = p0;
            *(short8*)&at[ii][jq + 8] = p1;
        }
        __syncthreads();
#pragma unroll
        for (int ks = 0; ks < 2; ++ks) {
            short8 af[2], bfr[4];
            af[0] = *(short8*)&at[wi + lq][ks * 32 + quad * 8];
            af[1] = *(short8*)&at[wi + 16 + lq][ks * 32 + quad * 8];
#pragma unroll
            for (int j = 0; j < 4; ++j)
                bfr[j] = *(short8*)&vt[wd + j * 16 + lq][ks * 32 + quad * 8];
#pragma unroll
            for (int i2 = 0; i2 < 2; ++i2)
#pragma unroll
                for (int j = 0; j < 4; ++j)
                    acc[i2][j] = __builtin_amdgcn_mfma_f32_16x16x32_bf16(
                        af[i2], bfr[j], acc[i2][j], 0, 0, 0);
        }
    }
#pragma unroll
    for (int i2 = 0; i2 < 2; ++i2) {
#pragma unroll
        for (int r = 0; r < 4; ++r) {
            int i = i0 + wi + i2 * 16 + quad * 4 + r;
            float* dst = obuf + ((size_t)(b * NT + i)) * DH + h * DHD + wd;
#pragma unroll
            for (int j = 0; j < 4; ++j)
                dst[j * 16 + lq] = acc[i2][j][r];
        }
    }
}

// ---------------- readout scores ----------------
__global__ __launch_bounds__(64) void score_kernel(
    const float* __restrict__ x, const float* __restrict__ rW,
    const float* __restrict__ rb, float* __restrict__ scores)
{
    int r = blockIdx.x;
    int lane = threadIdx.x;
    const float* xr = x + (size_t)r * DH;
    float acc = 0.f;
#pragma unroll
    for (int k = 0; k < 4; ++k) {
        float4 xv = *(const float4*)(xr + lane * 16 + k * 4);
        float4 wv = *(const float4*)(rW + lane * 16 + k * 4);
        acc += xv.x * wv.x + xv.y * wv.y + xv.z * wv.z + xv.w * wv.w;
    }
    for (int off = 32; off > 0; off >>= 1) acc += __shfl_down(acc, off, 64);
    if (lane == 0) scores[r] = acc + rb[0];
}

// ---------------- per-batch softmax over node scores ----------------
__global__ __launch_bounds__(256) void softmax_w(float* __restrict__ scores)
{
    __shared__ float red[256];
    int b = blockIdx.x;
    int tid = threadIdx.x;
    float* sr = scores + (size_t)b * NT;
    float v[4];
    float mx = -3e38f;
#pragma unroll
    for (int k = 0; k < 4; ++k) { v[k] = sr[tid + k * 256]; mx = fmaxf(mx, v[k]); }
    float m = block_reduce_max(mx, red);
    float ls = 0.f;
#pragma unroll
    for (int k = 0; k < 4; ++k) { v[k] = expf(v[k] - m); ls += v[k]; }
    float tot = block_reduce_sum(ls, red);
    float inv = 1.0f / tot;
#pragma unroll
    for (int k = 0; k < 4; ++k) sr[tid + k * 256] = v[k] * inv;
}

// ---------------- weighted pool partials ----------------
__global__ __launch_bounds__(256) void pool_part(
    const float* __restrict__ x, const float* __restrict__ w,
    float* __restrict__ gpart)
{
    int p = blockIdx.x;
    int b = blockIdx.y;
    int tid = threadIdx.x;
    float a0 = 0, a1 = 0, a2 = 0, a3 = 0;
    for (int n = p * 128; n < (p + 1) * 128; ++n) {
        float wv = w[(size_t)b * NT + n];
        float4 xv = *(const float4*)(x + ((size_t)(b * NT + n)) * DH + tid * 4);
        a0 += wv * xv.x; a1 += wv * xv.y; a2 += wv * xv.z; a3 += wv * xv.w;
    }
    float4 o = make_float4(a0, a1, a2, a3);
    *(float4*)(gpart + ((size_t)(b * 8 + p)) * DH + tid * 4) = o;
}

// ---------------- final candidate scorer ----------------
__global__ __launch_bounds__(256) void scorer_kernel(
    const float* __restrict__ gpart, const float* __restrict__ W1,
    const float* __restrict__ b1, const float* __restrict__ W2,
    const float* __restrict__ b2, float* __restrict__ out)
{
    __shared__ float gsh[DH];
    __shared__ float red[256];
    int b = blockIdx.x;
    int tid = threadIdx.x;
#pragma unroll
    for (int c = 0; c < 4; ++c) {
        int d = tid + c * 256;
        float gv = 0.f;
        for (int p = 0; p < 8; ++p) gv += gpart[((size_t)(b * 8 + p)) * DH + d];
        gsh[d] = gv;
    }
    __syncthreads();
    float acc[4] = {};
    for (int d = 0; d < DH; ++d) {
        float gv = gsh[d];
        const float* wr = W1 + (size_t)d * DH;
#pragma unroll
        for (int c = 0; c < 4; ++c) acc[c] += gv * wr[tid + c * 256];
    }
    float part = 0.f;
#pragma unroll
    for (int c = 0; c < 4; ++c) {
        int k = tid + c * 256;
        float u = acc[c] + b1[k];
        float inner = 0.7978845608028654f * (u + 0.044715f * u * u * u);
        float gel = 0.5f * u * (1.0f + tanhf(inner));
        part += gel * W2[k];
    }
    float tot = block_reduce_sum(part, red);
    if (tid == 0) out[b] = tot + b2[0];
}

// ---------------- launch ----------------
extern "C" void kernel_launch(void* const* d_in, const int* in_sizes, int n_in,
                              void* d_out, int out_size, void* d_ws, size_t ws_size,
                              hipStream_t stream)
{
    const float* visual   = (const float*)d_in[0];
    const int*   q_ids    = (const int*)d_in[1];
    const int*   q_mask   = (const int*)d_in[2];
    const float* kg_feat  = (const float*)d_in[3];
    const int*   adj      = (const int*)d_in[4];
    const int*   ntypes   = (const int*)d_in[5];
    const float* vis_W    = (const float*)d_in[6];
    const float* vis_b    = (const float*)d_in[7];
    const float* vis_lng  = (const float*)d_in[8];
    const float* vis_lnb  = (const float*)d_in[9];
    const float* tok_emb  = (const float*)d_in[10];
    const float* q_W      = (const float*)d_in[11];
    const float* q_b      = (const float*)d_in[12];
    const float* q_lng    = (const float*)d_in[13];
    const float* q_lnb    = (const float*)d_in[14];
    const float* kg_W     = (const float*)d_in[15];
    const float* kg_b     = (const float*)d_in[16];
    const float* kg_lng   = (const float*)d_in[17];
    const float* kg_lnb   = (const float*)d_in[18];
    const float* type_emb = (const float*)d_in[19];
    const float* gat_W    = (const float*)d_in[20];
    const float* gat_b    = (const float*)d_in[21];
    const float* a_src    = (const float*)d_in[22];
    const float* a_dst    = (const float*)d_in[23];
    const float* gat_lng  = (const float*)d_in[24];
    const float* gat_lnb  = (const float*)d_in[25];
    const float* read_W   = (const float*)d_in[26];
    const float* read_b   = (const float*)d_in[27];
    const float* cs_W1    = (const float*)d_in[28];
    const float* cs_b1    = (const float*)d_in[29];
    const float* cs_W2    = (const float*)d_in[30];
    const float* cs_b2    = (const float*)d_in[31];
    float* out = (float*)d_out;

    float* ws = (float*)d_ws;
    const size_t NROW = (size_t)NB * NT;              // 8192
    float* x      = ws;                               // 8M floats
    float* obuf   = x + NROW * DH;                    // 8M floats
    float* sbuf   = obuf + NROW * DH;                 // 64K
    float* tbuf   = sbuf + NB * NH * NT;
    float* mbuf   = tbuf + NB * NH * NT;
    float* lbuf   = mbuf + NB * NH * NT;
    float* pooled = lbuf + NB * NH * NT;
    float* scores = pooled + NB * DH;
    float* gpart  = scores + NROW;
    short* wt_gat = (short*)(gpart + NB * 8 * DH);    // 3M shorts
    short* ht     = wt_gat + (size_t)NLAYERS * DH * DH;   // 8M shorts
    unsigned* mb  = (unsigned*)(ht + (size_t)NB * NH * DHD * NT);  // 256K u32
    short* xb     = (short*)(mb + (size_t)NB * NT * 32);  // 8M shorts
    short* wt_vis = xb + NROW * DH;                   // 1024x2048
    short* wt_q   = wt_vis + (size_t)1024 * 2048;     // 1024x1024
    short* wt_kg  = wt_q + (size_t)1024 * 1024;       // 1024x320

    // 0. weight transpose-casts + adjacency bitmask
    transpose_cast<<<dim3(16, 32), 256, 0, stream>>>(vis_W, wt_vis, DV, DH, DV);
    transpose_cast<<<dim3(16, 16), 256, 0, stream>>>(q_W, wt_q, DH, DH, DH);
    transpose_cast<<<dim3(16, 5), 256, 0, stream>>>(kg_W, wt_kg, DK, DH, 320);
    for (int l = 0; l < NLAYERS; ++l)
        transpose_cast<<<dim3(16, 16), 256, 0, stream>>>(
            gat_W + (size_t)l * DH * DH, wt_gat + (size_t)l * DH * DH, DH, DH, DH);
    bitmask_kernel<<<NB * NT, 256, 0, stream>>>(adj, mb);

    // 1. visual projection + LN -> x[:, 0:100]
    gemm_bias_mfma<<<dim3(8, 7), 256, 0, stream>>>(
        visual, wt_vis, vis_b, obuf, NB * NV, DH, DV, DV, DV);
    ln_scatter<<<NB * NV, 256, 0, stream>>>(obuf, x, vis_lng, vis_lnb, NB * NV, NV, 0);

    // 2. text pool + proj + LN -> x[:, 100]
    pool_kernel<<<NB, 256, 0, stream>>>(tok_emb, q_ids, q_mask, pooled);
    gemm_bias_mfma<<<dim3(8, 1), 256, 0, stream>>>(
        pooled, wt_q, q_b, obuf, NB, DH, DH, DH, DH);
    ln_scatter<<<NB, 256, 0, stream>>>(obuf, x, q_lng, q_lnb, NB, 1, NV);

    // 3. KG projection + LN -> x[:, 101:1024]
    gemm_bias_mfma<<<dim3(8, 58), 256, 0, stream>>>(
        kg_feat, wt_kg, kg_b, obuf, NB * NKG, DH, DK, 320, DK);
    ln_scatter<<<NB * NKG, 256, 0, stream>>>(obuf, x, kg_lng, kg_lnb, NB * NKG, NKG, NV + 1);

    // 4. + type embeddings (also writes xb bf16)
    type_add<<<NB * NT, 256, 0, stream>>>(x, ntypes, type_emb, xb);

    // 5. GAT layers
    for (int l = 0; l < NLAYERS; ++l) {
        const float* bl  = gat_b + (size_t)l * DH;
        const float* asl = a_src + (size_t)l * NH * DHD;
        const float* adl = a_dst + (size_t)l * NH * DHD;
        gemm_st_mfma<<<dim3(NH, 64), 256, 0, stream>>>(
            xb, wt_gat + (size_t)l * DH * DH, bl, asl, adl, ht, sbuf, tbuf);
        stats_kernel<<<NB * NT, 256, 0, stream>>>(mb, sbuf, tbuf, mbuf, lbuf);
        agg_mfma<<<dim3(16, NH, NB), 256, 0, stream>>>(
            ht, mb, sbuf, tbuf, mbuf, lbuf, obuf);
        ln_residual<<<NB * NT, 256, 0, stream>>>(x, obuf,
            gat_lng + (size_t)l * DH, gat_lnb + (size_t)l * DH, xb);
    }

    // 6. readout + scorer
    score_kernel<<<NB * NT, 64, 0, stream>>>(x, read_W, read_b, scores);
    softmax_w<<<NB, 256, 0, stream>>>(scores);
    pool_part<<<dim3(8, NB), 256, 0, stream>>>(x, scores, gpart);
    scorer_kernel<<<NB, 256, 0, stream>>>(gpart, cs_W1, cs_b1, cs_W2, cs_b2, out);
}

// Round 6
// 1058.562 us; speedup vs baseline: 3.1122x; 1.0354x over previous
//
#include <hip/hip_runtime.h>
#include <math.h>

#define NB 8
#define NV 100
#define LQ 128
#define NKG 923
#define NT 1024
#define DV 2048
#define DK 300
#define DH 1024
#define NH 8
#define DHD 128
#define NLAYERS 3

typedef __attribute__((ext_vector_type(8))) short short8;
typedef __attribute__((ext_vector_type(4))) float f32x4;

__device__ __forceinline__ short f2bf(float f) {
    unsigned u = __float_as_uint(f);
    u += 0x7fff + ((u >> 16) & 1);   // round-to-nearest-even
    return (short)(u >> 16);
}
__device__ __forceinline__ float bf2f(short s) {
    unsigned u = ((unsigned)(unsigned short)s) << 16;
    return __uint_as_float(u);
}
__device__ __forceinline__ unsigned pack2(float a, float b) {
    return (unsigned)(unsigned short)f2bf(a) | ((unsigned)(unsigned short)f2bf(b) << 16);
}

#if __has_builtin(__builtin_amdgcn_global_load_lds)
#define HAVE_GLL 1
__device__ __forceinline__ void gll16(const void* g, void* l) {
    __builtin_amdgcn_global_load_lds(
        (const __attribute__((address_space(1))) void*)g,
        (__attribute__((address_space(3))) void*)l, 16, 0, 0);
}
#else
#define HAVE_GLL 0
#endif

// ---------------- block reduce helpers (blockDim.x == 256) ----------------
__device__ __forceinline__ float block_reduce_sum(float v, float* red) {
    int tid = threadIdx.x;
    red[tid] = v; __syncthreads();
    for (int s = 128; s > 0; s >>= 1) {
        if (tid < s) red[tid] += red[tid + s];
        __syncthreads();
    }
    float r = red[0]; __syncthreads();
    return r;
}
__device__ __forceinline__ float block_reduce_max(float v, float* red) {
    int tid = threadIdx.x;
    red[tid] = v; __syncthreads();
    for (int s = 128; s > 0; s >>= 1) {
        if (tid < s) red[tid] = fmaxf(red[tid], red[tid + s]);
        __syncthreads();
    }
    float r = red[0]; __syncthreads();
    return r;
}

// ---------------- adjacency -> bitmask ----------------
__global__ __launch_bounds__(256) void bitmask_kernel(
    const int* __restrict__ adj, unsigned* __restrict__ mb)
{
    int bi = blockIdx.x;
    int tid = threadIdx.x;
#pragma unroll
    for (int p = 0; p < 4; ++p) {
        int j = p * 256 + tid;
        unsigned long long bal = __ballot(adj[(size_t)bi * NT + j] > 0);
        if ((tid & 63) == 0) {
            int w = (p * 256 + (tid & 0xC0)) >> 5;
            mb[(size_t)bi * 32 + w]     = (unsigned)bal;
            mb[(size_t)bi * 32 + w + 1] = (unsigned)(bal >> 32);
        }
    }
}

// ---------------- weight transpose-cast: out[N,Kp] bf16 <- in[K,N] fp32 ----
__global__ __launch_bounds__(256) void transpose_cast(
    const float* __restrict__ in, short* __restrict__ out,
    int K, int N, int Kp)
{
    __shared__ float ls[64][65];
    int n0 = blockIdx.x * 64, k0 = blockIdx.y * 64;
    int tid = threadIdx.x;
    int j4 = (tid & 15) * 4;
#pragma unroll
    for (int s = 0; s < 4; ++s) {
        int i = (tid >> 4) + s * 16;
        int k = k0 + i;
        float4 v = make_float4(0.f, 0.f, 0.f, 0.f);
        if (k < K) v = *(const float4*)(in + (size_t)k * N + n0 + j4);
        ls[i][j4 + 0] = v.x; ls[i][j4 + 1] = v.y;
        ls[i][j4 + 2] = v.z; ls[i][j4 + 3] = v.w;
    }
    __syncthreads();
#pragma unroll
    for (int s = 0; s < 4; ++s) {
        int a = (tid >> 4) + s * 16;
        int b = (tid & 15) * 4;
        uint2 pk;
        pk.x = pack2(ls[b + 0][a], ls[b + 1][a]);
        pk.y = pack2(ls[b + 2][a], ls[b + 3][a]);
        *(uint2*)(out + (size_t)(n0 + a) * Kp + k0 + b) = pk;
    }
}

// ---------------- MFMA GEMM (fp32 A): C = A @ Wt^T + bias  (projections) ---
__global__ __launch_bounds__(256) void gemm_bias_mfma(
    const float* __restrict__ A, const short* __restrict__ Wt,
    const float* __restrict__ bias, float* __restrict__ C,
    int M, int N, int K, int Kp, int ldA)
{
    __shared__ short At[128][32];
    __shared__ short Bt[128][32];
    int tid = threadIdx.x;
    int row0 = blockIdx.y * 128, col0 = blockIdx.x * 128;
    int lane = tid & 63, wave = tid >> 6;
    int quad = lane >> 4, lq = lane & 15;
    int wm = (wave >> 1) * 64, wn = (wave & 1) * 64;
    f32x4 acc[4][4];
#pragma unroll
    for (int i = 0; i < 4; ++i)
#pragma unroll
        for (int j = 0; j < 4; ++j) {
            f32x4 z = {0.f, 0.f, 0.f, 0.f};
            acc[i][j] = z;
        }
    int ar = tid >> 2;
    int ac = (tid & 3) * 8;
    for (int k0 = 0; k0 < Kp; k0 += 32) {
        bool fullk = (k0 + 32 <= K);
#pragma unroll
        for (int s = 0; s < 2; ++s) {
            int r = ar + s * 64;
            int grow = row0 + r;
            short8 pk;
            if (grow < M && fullk) {
                const float* src = A + (size_t)grow * ldA + k0 + ac;
                float4 v0 = *(const float4*)(src);
                float4 v1 = *(const float4*)(src + 4);
                pk[0] = f2bf(v0.x); pk[1] = f2bf(v0.y);
                pk[2] = f2bf(v0.z); pk[3] = f2bf(v0.w);
                pk[4] = f2bf(v1.x); pk[5] = f2bf(v1.y);
                pk[6] = f2bf(v1.z); pk[7] = f2bf(v1.w);
            } else {
#pragma unroll
                for (int e = 0; e < 8; ++e) {
                    int k = k0 + ac + e;
                    pk[e] = (grow < M && k < K)
                          ? f2bf(A[(size_t)grow * ldA + k]) : (short)0;
                }
            }
            *(short8*)&At[r][ac] = pk;
        }
#pragma unroll
        for (int s = 0; s < 2; ++s) {
            int n = ar + s * 64;
            short8 w = *(const short8*)(Wt + (size_t)(col0 + n) * Kp + k0 + ac);
            *(short8*)&Bt[n][ac] = w;
        }
        __syncthreads();
        short8 af[4], bfr[4];
#pragma unroll
        for (int i = 0; i < 4; ++i)
            af[i] = *(short8*)&At[wm + i * 16 + lq][quad * 8];
#pragma unroll
        for (int j = 0; j < 4; ++j)
            bfr[j] = *(short8*)&Bt[wn + j * 16 + lq][quad * 8];
#pragma unroll
        for (int i = 0; i < 4; ++i)
#pragma unroll
            for (int j = 0; j < 4; ++j)
                acc[i][j] = __builtin_amdgcn_mfma_f32_16x16x32_bf16(
                    af[i], bfr[j], acc[i][j], 0, 0, 0);
        __syncthreads();
    }
#pragma unroll
    for (int j = 0; j < 4; ++j) {
        int n = col0 + wn + j * 16 + lq;
        float bv = bias[n];
#pragma unroll
        for (int i = 0; i < 4; ++i) {
#pragma unroll
            for (int r = 0; r < 4; ++r) {
                int m = row0 + wm + i * 16 + quad * 4 + r;
                if (m < M) C[(size_t)m * N + n] = acc[i][j][r] + bv;
            }
        }
    }
}

// ---------------- fused GAT gemm: h = xb@W^T+b, writes ht (bf16 [d][j]) + s,t
// grid (NH, M/128). LDS: ct aliases At/Bt (dead after K-loop) -> ~38 KB.
__global__ __launch_bounds__(256) void gemm_st_mfma(
    const short* __restrict__ Ab, const short* __restrict__ Wt,
    const float* __restrict__ bias,
    const float* __restrict__ asrc, const float* __restrict__ adst,
    short* __restrict__ ht,
    float* __restrict__ sbuf, float* __restrict__ tbuf)
{
    __shared__ __align__(16) short smem[17408];   // 34816 B
    short (*At)[32]  = (short(*)[32])smem;         // 8 KB (K-loop)
    short (*Bt)[32]  = (short(*)[32])(smem + 4096);// 8 KB (K-loop)
    short (*ct)[136] = (short(*)[136])smem;        // 34.8 KB (epilogue, aliases)
    __shared__ float sred[2][128], tred[2][128];
    __shared__ float asl[128], adl[128];
    int tid = threadIdx.x;
    int h = blockIdx.x;
    int row0 = blockIdx.y * 128, col0 = h * 128;
    int b = row0 >> 10, i0 = row0 & 1023;
    int lane = tid & 63, wave = tid >> 6;
    int quad = lane >> 4, lq = lane & 15;
    int wm = (wave >> 1) * 64, wn = (wave & 1) * 64;
    if (tid < 128) asl[tid] = asrc[h * DHD + tid];
    else adl[tid - 128] = adst[h * DHD + tid - 128];
    f32x4 acc[4][4];
#pragma unroll
    for (int i = 0; i < 4; ++i)
#pragma unroll
        for (int j = 0; j < 4; ++j) {
            f32x4 z = {0.f, 0.f, 0.f, 0.f};
            acc[i][j] = z;
        }

    const short* gA0 = Ab + (size_t)(row0 + wave * 16 + (lane >> 2)) * DH + (lane & 3) * 8;
    const short* gA1 = gA0 + (size_t)64 * DH;
    const short* gB0 = Wt + (size_t)(col0 + wave * 16 + (lane >> 2)) * DH + (lane & 3) * 8;
    const short* gB1 = gB0 + (size_t)64 * DH;
#if HAVE_GLL
    char* lA0 = (char*)At + wave * 1024; char* lA1 = lA0 + 4096;
    char* lB0 = (char*)Bt + wave * 1024; char* lB1 = lB0 + 4096;
#endif
    for (int k0 = 0; k0 < DH; k0 += 32) {
#if HAVE_GLL
        gll16(gA0 + k0, lA0); gll16(gA1 + k0, lA1);
        gll16(gB0 + k0, lB0); gll16(gB1 + k0, lB1);
#else
        {
            short8 va0 = *(const short8*)(gA0 + k0);
            short8 va1 = *(const short8*)(gA1 + k0);
            short8 vb0 = *(const short8*)(gB0 + k0);
            short8 vb1 = *(const short8*)(gB1 + k0);
            *(short8*)((char*)At + wave * 1024 + lane * 16) = va0;
            *(short8*)((char*)At + 4096 + wave * 1024 + lane * 16) = va1;
            *(short8*)((char*)Bt + wave * 1024 + lane * 16) = vb0;
            *(short8*)((char*)Bt + 4096 + wave * 1024 + lane * 16) = vb1;
        }
#endif
        __syncthreads();
        short8 af[4], bfr[4];
#pragma unroll
        for (int i = 0; i < 4; ++i)
            af[i] = *(short8*)&At[wm + i * 16 + lq][quad * 8];
#pragma unroll
        for (int j = 0; j < 4; ++j)
            bfr[j] = *(short8*)&Bt[wn + j * 16 + lq][quad * 8];
#pragma unroll
        for (int i = 0; i < 4; ++i)
#pragma unroll
            for (int j = 0; j < 4; ++j)
                acc[i][j] = __builtin_amdgcn_mfma_f32_16x16x32_bf16(
                    af[i], bfr[j], acc[i][j], 0, 0, 0);
        __syncthreads();
    }
    // epilogue 1: bias + bf16, store transposed tile ct[d][i] (aliases At/Bt)
#pragma unroll
    for (int j = 0; j < 4; ++j) {
        int d = wn + j * 16 + lq;
        float bv = bias[col0 + d];
#pragma unroll
        for (int i2 = 0; i2 < 4; ++i2) {
            int m = wm + i2 * 16 + quad * 4;
            uint2 pk;
            pk.x = pack2(acc[i2][j][0] + bv, acc[i2][j][1] + bv);
            pk.y = pack2(acc[i2][j][2] + bv, acc[i2][j][3] + bv);
            *(uint2*)&ct[d][m] = pk;
        }
    }
    __syncthreads();
    // epilogue 2: ht global store
    {
        int d = tid >> 1, half = tid & 1;
        short* dst = ht + ((size_t)(b * NH + h) * DHD + d) * NT + i0 + half * 64;
        const short* src = &ct[d][half * 64];
#pragma unroll
        for (int q = 0; q < 8; ++q)
            *(short8*)(dst + q * 8) = *(const short8*)(src + q * 8);
    }
    // epilogue 3: s,t from ct
    {
        int i = tid >> 1, half = tid & 1;
        float sa = 0.f, ta = 0.f;
#pragma unroll 16
        for (int dd = 0; dd < 64; ++dd) {
            int d = half * 64 + dd;
            float hv = bf2f(ct[d][i]);
            sa += hv * asl[d];
            ta += hv * adl[d];
        }
        sred[half][i] = sa; tred[half][i] = ta;
    }
    __syncthreads();
    if (tid < 128) {
        size_t idx = (size_t)(b * NH + h) * NT + i0 + tid;
        sbuf[idx] = sred[0][tid] + sred[1][tid];
        tbuf[idx] = tred[0][tid] + tred[1][tid];
    }
}

// ---------------- LayerNorm + scatter into x ----------------
__global__ __launch_bounds__(256) void ln_scatter(
    const float* __restrict__ src, float* __restrict__ x,
    const float* __restrict__ g, const float* __restrict__ bta,
    int rows, int npb, int node_off)
{
    __shared__ float red[256];
    int r = blockIdx.x;
    if (r >= rows) return;
    int tid = threadIdx.x;
    int b = r / npb, n = r % npb;
    float4 v = *(const float4*)(src + (size_t)r * DH + tid * 4);
    float s = v.x + v.y + v.z + v.w;
    float sq = v.x * v.x + v.y * v.y + v.z * v.z + v.w * v.w;
    float tot = block_reduce_sum(s, red);
    float totsq = block_reduce_sum(sq, red);
    float mean = tot * (1.0f / DH);
    float var = totsq * (1.0f / DH) - mean * mean;
    float rstd = 1.0f / sqrtf(var + 1e-5f);
    float4 gv = *(const float4*)(g + tid * 4);
    float4 bv = *(const float4*)(bta + tid * 4);
    float4 o;
    o.x = (v.x - mean) * rstd * gv.x + bv.x;
    o.y = (v.y - mean) * rstd * gv.y + bv.y;
    o.z = (v.z - mean) * rstd * gv.z + bv.z;
    o.w = (v.w - mean) * rstd * gv.w + bv.w;
    *(float4*)(x + ((size_t)(b * NT + node_off + n)) * DH + tid * 4) = o;
}

// ---------------- residual+LN (+ optional readout score fused on last layer)
__global__ __launch_bounds__(256) void ln_residual(
    float* __restrict__ x, const float* __restrict__ o,
    const float* __restrict__ g, const float* __restrict__ bta,
    short* __restrict__ xb,
    const float* __restrict__ rW, const float* __restrict__ rb,
    float* __restrict__ scores)
{
    __shared__ float red[256];
    int r = blockIdx.x;
    int tid = threadIdx.x;
    float* xr = x + (size_t)r * DH;
    float4 xv = *(float4*)(xr + tid * 4);
    float4 ov = *(const float4*)(o + (size_t)r * DH + tid * 4);
    float v0 = xv.x + ov.x, v1 = xv.y + ov.y, v2 = xv.z + ov.z, v3 = xv.w + ov.w;
    float s = v0 + v1 + v2 + v3;
    float sq = v0 * v0 + v1 * v1 + v2 * v2 + v3 * v3;
    float tot = block_reduce_sum(s, red);
    float totsq = block_reduce_sum(sq, red);
    float mean = tot * (1.0f / DH);
    float var = totsq * (1.0f / DH) - mean * mean;
    float rstd = 1.0f / sqrtf(var + 1e-5f);
    float4 gv = *(const float4*)(g + tid * 4);
    float4 bv = *(const float4*)(bta + tid * 4);
    float4 out;
    out.x = (v0 - mean) * rstd * gv.x + bv.x;
    out.y = (v1 - mean) * rstd * gv.y + bv.y;
    out.z = (v2 - mean) * rstd * gv.z + bv.z;
    out.w = (v3 - mean) * rstd * gv.w + bv.w;
    *(float4*)(xr + tid * 4) = out;
    uint2 pk;
    pk.x = pack2(out.x, out.y);
    pk.y = pack2(out.z, out.w);
    *(uint2*)(xb + (size_t)r * DH + tid * 4) = pk;
    if (scores) {
        float4 wv = *(const float4*)(rW + tid * 4);
        float p = out.x * wv.x + out.y * wv.y + out.z * wv.z + out.w * wv.w;
        float totp = block_reduce_sum(p, red);
        if (tid == 0) scores[r] = totp + rb[0];
    }
}

// ---------------- text: masked mean pool ----------------
__global__ __launch_bounds__(256) void pool_kernel(
    const float* __restrict__ tok_emb, const int* __restrict__ ids,
    const int* __restrict__ amask, float* __restrict__ pooled)
{
    int b = blockIdx.x;
    int tid = threadIdx.x;
    float a0 = 0, a1 = 0, a2 = 0, a3 = 0;
    float denom = 0;
    for (int l = 0; l < LQ; ++l) {
        int id = ids[b * LQ + l];
        float m = (float)amask[b * LQ + l];
        denom += m;
        float4 e = *(const float4*)(tok_emb + (size_t)id * DH + tid * 4);
        a0 += m * e.x; a1 += m * e.y; a2 += m * e.z; a3 += m * e.w;
    }
    float inv = 1.0f / fmaxf(denom, 1.0f);
    float4 o = make_float4(a0 * inv, a1 * inv, a2 * inv, a3 * inv);
    *(float4*)(pooled + b * DH + tid * 4) = o;
}

// ---------------- add type embeddings, write x and xb ----------------
__global__ __launch_bounds__(256) void type_add(
    float* __restrict__ x, const int* __restrict__ types,
    const float* __restrict__ type_emb, short* __restrict__ xb)
{
    int r = blockIdx.x;
    int tid = threadIdx.x;
    int ty = types[r];
    float4 xv = *(float4*)(x + (size_t)r * DH + tid * 4);
    float4 tv = *(const float4*)(type_emb + (size_t)ty * DH + tid * 4);
    xv.x += tv.x; xv.y += tv.y; xv.z += tv.z; xv.w += tv.w;
    *(float4*)(x + (size_t)r * DH + tid * 4) = xv;
    uint2 pk;
    pk.x = pack2(xv.x, xv.y);
    pk.y = pack2(xv.z, xv.w);
    *(uint2*)(xb + (size_t)r * DH + tid * 4) = pk;
}

// ---------------- GAT aggregation: MFMA + online softmax (flash-style) ------
// grid (NT/64, NH, NB). Per-i running m,l; acc rescaled via LDS alpha.
__global__ __launch_bounds__(256) void agg_mfma(
    const short* __restrict__ ht, const unsigned* __restrict__ mb,
    const float* __restrict__ s, const float* __restrict__ t,
    float* __restrict__ obuf)
{
    __shared__ short vt[128][72];
    __shared__ short at[64][72];
    __shared__ unsigned mrow[64][32];
    __shared__ float sv[64], alpha_s[64], lfin[64];
    int i0 = blockIdx.x * 64;
    int h = blockIdx.y, b = blockIdx.z;
    int tid = threadIdx.x;
    int lane = tid & 63, wave = tid >> 6;
    int quad = lane >> 4, lq = lane & 15;
    int wi = (wave >> 1) * 32;
    int wd = (wave & 1) * 64;
    if (tid < 64) sv[tid] = s[(size_t)(b * NH + h) * NT + i0 + tid];
#pragma unroll
    for (int s2 = 0; s2 < 2; ++s2) {
        int f = tid + s2 * 256;
        int ii2 = f >> 3, w4 = (f & 7) * 4;
        *(uint4*)&mrow[ii2][w4] =
            *(const uint4*)(mb + ((size_t)(b * NT + i0 + ii2)) * 32 + w4);
    }
    const float* tptr = t + (size_t)(b * NH + h) * NT;
    const short* hbase = ht + ((size_t)(b * NH + h) * DHD) * NT;
    f32x4 acc[2][4];
#pragma unroll
    for (int i = 0; i < 2; ++i)
#pragma unroll
        for (int j = 0; j < 4; ++j) {
            f32x4 z = {0.f, 0.f, 0.f, 0.f};
            acc[i][j] = z;
        }
    int ii = tid >> 2;             // at row this thread fills
    int jq = (tid & 3) * 16;       // 16 j's per thread
    float m_run = -3e38f, l_run = 0.f;
    for (int j0 = 0; j0 < NT; j0 += 64) {
        __syncthreads();           // protect LDS from previous iter's reads
        // stage vt: 128 d x 64 j bf16
#pragma unroll
        for (int s2 = 0; s2 < 4; ++s2) {
            int f = tid + s2 * 256;
            int d = f >> 3, c = (f & 7) * 8;
            *(short8*)&vt[d][c] = *(const short8*)(hbase + (size_t)d * NT + j0 + c);
        }
        // scores for this thread's 16 j
        float vv[16];
        unsigned mw;
        float tmax = -3e38f;
        {
            mw = mrow[ii][(j0 + jq) >> 5] >> ((j0 + jq) & 31);
            float svv = sv[ii];
            float4 t0 = *(const float4*)(tptr + j0 + jq);
            float4 t1 = *(const float4*)(tptr + j0 + jq + 4);
            float4 t2 = *(const float4*)(tptr + j0 + jq + 8);
            float4 t3 = *(const float4*)(tptr + j0 + jq + 12);
            float tv16[16] = {t0.x, t0.y, t0.z, t0.w, t1.x, t1.y, t1.z, t1.w,
                              t2.x, t2.y, t2.z, t2.w, t3.x, t3.y, t3.z, t3.w};
#pragma unroll
            for (int e = 0; e < 16; ++e) {
                float v = svv + tv16[e];
                v = v > 0.f ? v : 0.2f * v;
                v = ((mw >> e) & 1) ? v : -1e9f;
                vv[e] = v;
                tmax = fmaxf(tmax, v);
            }
        }
        // reduce max over the 4 lanes of this row (consecutive lanes)
        tmax = fmaxf(tmax, __shfl_xor(tmax, 1, 64));
        tmax = fmaxf(tmax, __shfl_xor(tmax, 2, 64));
        float m_new = fmaxf(m_run, tmax);
        float al = __expf(m_run - m_new);   // first iter: exp(-inf) = 0
        float tsum = 0.f;
        short8 p0, p1;
#pragma unroll
        for (int e = 0; e < 8; ++e) {
            float w = ((mw >> e) & 1) ? __expf(vv[e] - m_new) : 0.f;
            tsum += w; p0[e] = f2bf(w);
        }
#pragma unroll
        for (int e = 0; e < 8; ++e) {
            float w = ((mw >> (8 + e)) & 1) ? __expf(vv[8 + e] - m_new) : 0.f;
            tsum += w; p1[e] = f2bf(w);
        }
        tsum += __shfl_xor(tsum, 1, 64);
        tsum += __shfl_xor(tsum, 2, 64);
        l_run = l_run * al + tsum;
        m_run = m_new;
        *(short8*)&at[ii][jq] = p0;
        *(short8*)&at[ii][jq + 8] = p1;
        if ((tid & 3) == 0) alpha_s[ii] = al;
        __syncthreads();
        // rescale acc by per-row alpha
#pragma unroll
        for (int i2 = 0; i2 < 2; ++i2)
#pragma unroll
            for (int r = 0; r < 4; ++r) {
                float arow = alpha_s[wi + i2 * 16 + quad * 4 + r];
#pragma unroll
                for (int j = 0; j < 4; ++j) acc[i2][j][r] *= arow;
            }
        // MFMA over this j-tile: 2 k-steps of 32
#pragma unroll
        for (int ks = 0; ks < 2; ++ks) {
            short8 af[2], bfr[4];
            af[0] = *(short8*)&at[wi + lq][ks * 32 + quad * 8];
            af[1] = *(short8*)&at[wi + 16 + lq][ks * 32 + quad * 8];
#pragma unroll
            for (int j = 0; j < 4; ++j)
                bfr[j] = *(short8*)&vt[wd + j * 16 + lq][ks * 32 + quad * 8];
#pragma unroll
            for (int i2 = 0; i2 < 2; ++i2)
#pragma unroll
                for (int j = 0; j < 4; ++j)
                    acc[i2][j] = __builtin_amdgcn_mfma_f32_16x16x32_bf16(
                        af[i2], bfr[j], acc[i2][j], 0, 0, 0);
        }
    }
    if ((tid & 3) == 0) lfin[ii] = l_run;
    __syncthreads();
#pragma unroll
    for (int i2 = 0; i2 < 2; ++i2) {
#pragma unroll
        for (int r = 0; r < 4; ++r) {
            int il = wi + i2 * 16 + quad * 4 + r;
            float inv = 1.0f / lfin[il];
            float* dst = obuf + ((size_t)(b * NT + i0 + il)) * DH + h * DHD + wd;
#pragma unroll
            for (int j = 0; j < 4; ++j)
                dst[j * 16 + lq] = acc[i2][j][r] * inv;
        }
    }
}

// ---------------- weighted pool partials (softmax of raw scores inline) -----
__global__ __launch_bounds__(256) void pool_part(
    const float* __restrict__ x, const float* __restrict__ scores,
    float* __restrict__ gpart)
{
    __shared__ float red[256];
    int p = blockIdx.x;
    int b = blockIdx.y;
    int tid = threadIdx.x;
    const float* sr = scores + (size_t)b * NT;
    float v[4];
    float mx = -3e38f;
#pragma unroll
    for (int k = 0; k < 4; ++k) { v[k] = sr[tid + k * 256]; mx = fmaxf(mx, v[k]); }
    float m = block_reduce_max(mx, red);
    float ls = 0.f;
#pragma unroll
    for (int k = 0; k < 4; ++k) ls += expf(v[k] - m);
    float tot = block_reduce_sum(ls, red);
    float inv = 1.0f / tot;
    float a0 = 0, a1 = 0, a2 = 0, a3 = 0;
    for (int n = p * 128; n < (p + 1) * 128; ++n) {
        float wv = expf(sr[n] - m) * inv;
        float4 xv = *(const float4*)(x + ((size_t)(b * NT + n)) * DH + tid * 4);
        a0 += wv * xv.x; a1 += wv * xv.y; a2 += wv * xv.z; a3 += wv * xv.w;
    }
    float4 o = make_float4(a0, a1, a2, a3);
    *(float4*)(gpart + ((size_t)(b * 8 + p)) * DH + tid * 4) = o;
}

// ---------------- final candidate scorer ----------------
__global__ __launch_bounds__(256) void scorer_kernel(
    const float* __restrict__ gpart, const float* __restrict__ W1,
    const float* __restrict__ b1, const float* __restrict__ W2,
    const float* __restrict__ b2, float* __restrict__ out)
{
    __shared__ float gsh[DH];
    __shared__ float red[256];
    int b = blockIdx.x;
    int tid = threadIdx.x;
#pragma unroll
    for (int c = 0; c < 4; ++c) {
        int d = tid + c * 256;
        float gv = 0.f;
        for (int p = 0; p < 8; ++p) gv += gpart[((size_t)(b * 8 + p)) * DH + d];
        gsh[d] = gv;
    }
    __syncthreads();
    float acc[4] = {};
    for (int d = 0; d < DH; ++d) {
        float gv = gsh[d];
        const float* wr = W1 + (size_t)d * DH;
#pragma unroll
        for (int c = 0; c < 4; ++c) acc[c] += gv * wr[tid + c * 256];
    }
    float part = 0.f;
#pragma unroll
    for (int c = 0; c < 4; ++c) {
        int k = tid + c * 256;
        float u = acc[c] + b1[k];
        float inner = 0.7978845608028654f * (u + 0.044715f * u * u * u);
        float gel = 0.5f * u * (1.0f + tanhf(inner));
        part += gel * W2[k];
    }
    float tot = block_reduce_sum(part, red);
    if (tid == 0) out[b] = tot + b2[0];
}

// ---------------- launch ----------------
extern "C" void kernel_launch(void* const* d_in, const int* in_sizes, int n_in,
                              void* d_out, int out_size, void* d_ws, size_t ws_size,
                              hipStream_t stream)
{
    const float* visual   = (const float*)d_in[0];
    const int*   q_ids    = (const int*)d_in[1];
    const int*   q_mask   = (const int*)d_in[2];
    const float* kg_feat  = (const float*)d_in[3];
    const int*   adj      = (const int*)d_in[4];
    const int*   ntypes   = (const int*)d_in[5];
    const float* vis_W    = (const float*)d_in[6];
    const float* vis_b    = (const float*)d_in[7];
    const float* vis_lng  = (const float*)d_in[8];
    const float* vis_lnb  = (const float*)d_in[9];
    const float* tok_emb  = (const float*)d_in[10];
    const float* q_W      = (const float*)d_in[11];
    const float* q_b      = (const float*)d_in[12];
    const float* q_lng    = (const float*)d_in[13];
    const float* q_lnb    = (const float*)d_in[14];
    const float* kg_W     = (const float*)d_in[15];
    const float* kg_b     = (const float*)d_in[16];
    const float* kg_lng   = (const float*)d_in[17];
    const float* kg_lnb   = (const float*)d_in[18];
    const float* type_emb = (const float*)d_in[19];
    const float* gat_W    = (const float*)d_in[20];
    const float* gat_b    = (const float*)d_in[21];
    const float* a_src    = (const float*)d_in[22];
    const float* a_dst    = (const float*)d_in[23];
    const float* gat_lng  = (const float*)d_in[24];
    const float* gat_lnb  = (const float*)d_in[25];
    const float* read_W   = (const float*)d_in[26];
    const float* read_b   = (const float*)d_in[27];
    const float* cs_W1    = (const float*)d_in[28];
    const float* cs_b1    = (const float*)d_in[29];
    const float* cs_W2    = (const float*)d_in[30];
    const float* cs_b2    = (const float*)d_in[31];
    float* out = (float*)d_out;

    float* ws = (float*)d_ws;
    const size_t NROW = (size_t)NB * NT;              // 8192
    float* x      = ws;                               // 8M floats
    float* obuf   = x + NROW * DH;                    // 8M floats
    float* sbuf   = obuf + NROW * DH;                 // 64K
    float* tbuf   = sbuf + NB * NH * NT;
    float* pooled = tbuf + NB * NH * NT;
    float* scores = pooled + NB * DH;
    float* gpart  = scores + NROW;
    short* wt_gat = (short*)(gpart + NB * 8 * DH);    // 3M shorts
    short* ht     = wt_gat + (size_t)NLAYERS * DH * DH;   // 8M shorts
    unsigned* mb  = (unsigned*)(ht + (size_t)NB * NH * DHD * NT);  // 256K u32
    short* xb     = (short*)(mb + (size_t)NB * NT * 32);  // 8M shorts
    short* wt_vis = xb + NROW * DH;                   // 1024x2048
    short* wt_q   = wt_vis + (size_t)1024 * 2048;     // 1024x1024
    short* wt_kg  = wt_q + (size_t)1024 * 1024;       // 1024x320

    // 0. weight transpose-casts + adjacency bitmask
    transpose_cast<<<dim3(16, 32), 256, 0, stream>>>(vis_W, wt_vis, DV, DH, DV);
    transpose_cast<<<dim3(16, 16), 256, 0, stream>>>(q_W, wt_q, DH, DH, DH);
    transpose_cast<<<dim3(16, 5), 256, 0, stream>>>(kg_W, wt_kg, DK, DH, 320);
    for (int l = 0; l < NLAYERS; ++l)
        transpose_cast<<<dim3(16, 16), 256, 0, stream>>>(
            gat_W + (size_t)l * DH * DH, wt_gat + (size_t)l * DH * DH, DH, DH, DH);
    bitmask_kernel<<<NB * NT, 256, 0, stream>>>(adj, mb);

    // 1. visual projection + LN -> x[:, 0:100]
    gemm_bias_mfma<<<dim3(8, 7), 256, 0, stream>>>(
        visual, wt_vis, vis_b, obuf, NB * NV, DH, DV, DV, DV);
    ln_scatter<<<NB * NV, 256, 0, stream>>>(obuf, x, vis_lng, vis_lnb, NB * NV, NV, 0);

    // 2. text pool + proj + LN -> x[:, 100]
    pool_kernel<<<NB, 256, 0, stream>>>(tok_emb, q_ids, q_mask, pooled);
    gemm_bias_mfma<<<dim3(8, 1), 256, 0, stream>>>(
        pooled, wt_q, q_b, obuf, NB, DH, DH, DH, DH);
    ln_scatter<<<NB, 256, 0, stream>>>(obuf, x, q_lng, q_lnb, NB, 1, NV);

    // 3. KG projection + LN -> x[:, 101:1024]
    gemm_bias_mfma<<<dim3(8, 58), 256, 0, stream>>>(
        kg_feat, wt_kg, kg_b, obuf, NB * NKG, DH, DK, 320, DK);
    ln_scatter<<<NB * NKG, 256, 0, stream>>>(obuf, x, kg_lng, kg_lnb, NB * NKG, NKG, NV + 1);

    // 4. + type embeddings (also writes xb bf16)
    type_add<<<NB * NT, 256, 0, stream>>>(x, ntypes, type_emb, xb);

    // 5. GAT layers (stats fused into agg via online softmax)
    for (int l = 0; l < NLAYERS; ++l) {
        const float* bl  = gat_b + (size_t)l * DH;
        const float* asl = a_src + (size_t)l * NH * DHD;
        const float* adl = a_dst + (size_t)l * NH * DHD;
        gemm_st_mfma<<<dim3(NH, 64), 256, 0, stream>>>(
            xb, wt_gat + (size_t)l * DH * DH, bl, asl, adl, ht, sbuf, tbuf);
        agg_mfma<<<dim3(16, NH, NB), 256, 0, stream>>>(
            ht, mb, sbuf, tbuf, obuf);
        ln_residual<<<NB * NT, 256, 0, stream>>>(x, obuf,
            gat_lng + (size_t)l * DH, gat_lnb + (size_t)l * DH, xb,
            read_W, read_b, (l == NLAYERS - 1) ? scores : nullptr);
    }

    // 6. readout + scorer (scores raw; pool_part does softmax inline)
    pool_part<<<dim3(8, NB), 256, 0, stream>>>(x, scores, gpart);
    scorer_kernel<<<NB, 256, 0, stream>>>(gpart, cs_W1, cs_b1, cs_W2, cs_b2, out);
}